// Round 9
// baseline (359.969 us; speedup 1.0000x reference)
//
#include <hip/hip_runtime.h>

typedef unsigned short u16;
typedef unsigned char u8;
typedef signed char s8;
typedef unsigned int u32;
typedef short bf16x8 __attribute__((ext_vector_type(8)));
typedef float f32x4 __attribute__((ext_vector_type(4)));
typedef int i32x4 __attribute__((ext_vector_type(4)));

#define SXI 21.1666667f     /* 127/6.0  : x quant */
#define SWI 1058.3333f      /* 127/0.12 : W quant */
#define DEQ 4.4640015e-5f   /* (6.0*0.12)/(127*127) */

__device__ __forceinline__ u16 f2bf(float f) {
  union { float f; u32 u; } v; v.f = f;
  u32 r = v.u + 0x7fffu + ((v.u >> 16) & 1u);
  return (u16)(r >> 16);
}
__device__ __forceinline__ s8 q8(float v, float s) {
  float x = fminf(127.f, fmaxf(-127.f, v * s));
  return (s8)__float2int_rn(x);
}
__device__ __forceinline__ float fexp2(float x) {
#if __has_builtin(__builtin_amdgcn_exp2f)
  return __builtin_amdgcn_exp2f(x);
#else
  return exp2f(x);
#endif
}
__device__ __forceinline__ u32 cvtpk_bf16(float lo, float hi) {
  u32 r;
  asm("v_cvt_pk_bf16_f32 %0, %1, %2" : "=v"(r) : "v"(lo), "v"(hi));
  return r;
}

__device__ __forceinline__ void gld_lds16(const u16* g, u16* l) {
  __builtin_amdgcn_global_load_lds(
      (__attribute__((address_space(1))) u32*)(g),
      (__attribute__((address_space(3))) u32*)(l), 16, 0, 0);
}
__device__ __forceinline__ void gld_lds16b(const u8* g, u8* l) {
  __builtin_amdgcn_global_load_lds(
      (__attribute__((address_space(1))) u32*)(g),
      (__attribute__((address_space(3))) u32*)(l), 16, 0, 0);
}

// bf16 tiles: rows of 64 bf16 = 8 x 16B chunks, phys chunk = c ^ (row&7)
__device__ __forceinline__ bf16x8 ldsfrag(const u16* base, int row, int c8) {
  return *(const bf16x8*)(base + row * 64 + ((c8 ^ (row & 7)) << 3));
}
// i8 tiles: rows of 64 i8 = 4 x 16B chunks, phys chunk = c ^ swz4(row)
__device__ __forceinline__ int swz4(int r) { return (r & 3) ^ ((r >> 2) & 3); }

// ---------------- prep: x->bf16+i8, W_attn^T (qk i8, v bf16), W_proj^T,
// + zero the 512 split-merge completion flags (workspace is re-poisoned each
// iteration, so zeroing must happen in-stream before k_attn).
__global__ __launch_bounds__(256) void k_prep(const float* __restrict__ x, u16* __restrict__ xb,
                                              s8* __restrict__ xq,
                                              const float* __restrict__ Wa, u16* __restrict__ WaT,
                                              s8* __restrict__ wq8,
                                              const float* __restrict__ Wp, u16* __restrict__ WpT,
                                              u32* __restrict__ pflag) {
  __shared__ float t[64][65];
  const int id = blockIdx.x;
  if (id < 2048) {
    if (id == 0) {
      pflag[threadIdx.x] = 0u;
      pflag[threadIdx.x + 256] = 0u;
    }
    int i = (id * 256 + threadIdx.x) * 8;
    const float4* p = (const float4*)(x + i);
    float4 a = p[0], b = p[1];
    uint4 o;
    o.x = (u32)f2bf(a.x) | ((u32)f2bf(a.y) << 16);
    o.y = (u32)f2bf(a.z) | ((u32)f2bf(a.w) << 16);
    o.z = (u32)f2bf(b.x) | ((u32)f2bf(b.y) << 16);
    o.w = (u32)f2bf(b.z) | ((u32)f2bf(b.w) << 16);
    *(uint4*)(xb + i) = o;
    u32 lo = (u32)(u8)q8(a.x, SXI) | ((u32)(u8)q8(a.y, SXI) << 8) |
             ((u32)(u8)q8(a.z, SXI) << 16) | ((u32)(u8)q8(a.w, SXI) << 24);
    u32 hi = (u32)(u8)q8(b.x, SXI) | ((u32)(u8)q8(b.y, SXI) << 8) |
             ((u32)(u8)q8(b.z, SXI) << 16) | ((u32)(u8)q8(b.w, SXI) << 24);
    uint2 oq; oq.x = lo; oq.y = hi;
    *(uint2*)(xq + i) = oq;
  } else if (id < 2816) {
    int q = id - 2048;
    int bx = q % 48, by = q / 48;
    int c0 = bx * 64, r0 = by * 64;
    int tx = threadIdx.x & 63, ty = threadIdx.x >> 6;
#pragma unroll
    for (int i = ty; i < 64; i += 4) t[i][tx] = Wa[(size_t)(r0 + i) * 3072 + c0 + tx];
    __syncthreads();
#pragma unroll
    for (int i = ty; i < 64; i += 4) {
      int row = c0 + i;
      if (row < 2048)
        wq8[(size_t)row * 1024 + r0 + tx] = q8(t[tx][i], SWI);
      else
        WaT[(size_t)row * 1024 + r0 + tx] = f2bf(t[tx][i]);
    }
  } else {
    int q = id - 2816;
    int bx = q & 15, by = q >> 4;
    int c0 = bx * 64, r0 = by * 64;
    int tx = threadIdx.x & 63, ty = threadIdx.x >> 6;
#pragma unroll
    for (int i = ty; i < 64; i += 4) t[i][tx] = Wp[(size_t)(r0 + i) * 1024 + c0 + tx];
    __syncthreads();
#pragma unroll
    for (int i = ty; i < 64; i += 4)
      WpT[(size_t)(c0 + i) * 1024 + r0 + tx] = f2bf(t[tx][i]);
  }
}

// ---------------- GEMM1: R4 verbatim (64x128 tiles, 1536 blocks, 6/CU, BK=64) ----------------
__global__ __launch_bounds__(256) void k_gemm_qkv(const u16* __restrict__ xb,
                                                  const s8* __restrict__ xq,
                                                  const u16* __restrict__ Wt,
                                                  const s8* __restrict__ wq8,
                                                  const float* __restrict__ bias,
                                                  u16* __restrict__ qb, u16* __restrict__ kb,
                                                  u16* __restrict__ vtb) {
  const int id = blockIdx.x;
  const int tid = threadIdx.x;
  const int lane = tid & 63, w = tid >> 6;
  const int lr = lane & 15, lq = lane >> 4;

  if (id < 1024) {
    // ---- int8 qk: 64x128 tile. C[t][n], n in [0,2048) ----
    __shared__ __align__(16) u8 la8[64 * 64], lb8[128 * 64];  // 12KB
    const int wm = (w >> 1) << 5, wn = (w & 1) << 6;
    i32x4 acc[2][4];
#pragma unroll
    for (int mi = 0; mi < 2; ++mi)
#pragma unroll
      for (int ni = 0; ni < 4; ++ni) acc[mi][ni] = (i32x4){0, 0, 0, 0};
    const int m0 = (id >> 4) * 64, n0 = (id & 15) * 128;
    const int srow4 = tid >> 2;  // 0..63
    const int gcol4 = (((tid & 3) ^ swz4(srow4)) << 4);
    const u8* ag = (const u8*)xq + (size_t)(m0 + srow4) * 1024 + gcol4;
    const u8* bg = (const u8*)wq8 + (size_t)(n0 + srow4) * 1024 + gcol4;

    for (int k0 = 0; k0 < 1024; k0 += 64) {
      __syncthreads();
      gld_lds16b(ag + k0, la8 + (w * 16) * 64);
#pragma unroll
      for (int r = 0; r < 2; ++r)
        gld_lds16b(bg + (size_t)r * 64 * 1024 + k0, lb8 + (r * 64 + w * 16) * 64);
      __syncthreads();
      i32x4 a[2], b[4];
#pragma unroll
      for (int mi = 0; mi < 2; ++mi) {
        int m = wm + mi * 16 + lr;
        a[mi] = *(const i32x4*)(la8 + m * 64 + ((lq ^ swz4(m)) << 4));
      }
#pragma unroll
      for (int ni = 0; ni < 4; ++ni) {
        int n = wn + ni * 16 + lr;
        b[ni] = *(const i32x4*)(lb8 + n * 64 + ((lq ^ swz4(n)) << 4));
      }
#pragma unroll
      for (int mi = 0; mi < 2; ++mi)
#pragma unroll
        for (int ni = 0; ni < 4; ++ni)
          acc[mi][ni] = __builtin_amdgcn_mfma_i32_16x16x64_i8(a[mi], b[ni], acc[mi][ni], 0, 0, 0);
    }
#pragma unroll
    for (int mi = 0; mi < 2; ++mi) {
      int gm = m0 + wm + mi * 16 + lq * 4;
#pragma unroll
      for (int ni = 0; ni < 4; ++ni) {
        int gn = n0 + wn + ni * 16 + lr;
        float bv = bias[gn];
        int which = gn >> 10, head = (gn >> 6) & 15, hd = gn & 63;
#pragma unroll
        for (int r = 0; r < 4; ++r) {
          int row = gm + r;
          int b2 = row >> 11, tt = row & 2047;
          float v = (float)acc[mi][ni][r] * DEQ + bv;
          size_t bh = (size_t)(b2 * 16 + head);
          if (which == 0)
            qb[(bh * 2048 + tt) * 64 + hd] = f2bf(v * 0.18033688f);  // fold 1/sqrt(64)*log2(e)
          else
            kb[(bh * 2048 + tt) * 64 + hd] = f2bf(v);
        }
      }
    }
  } else {
    // ---- bf16 v^T: 64x128 tile. A = WaT rows 2048.. (M=1024=dv), Bt = xb (N=4096=t) ----
    __shared__ u16 sA[64 * 64], sB[128 * 64];  // 24KB
    const int wm = (w >> 1) << 5, wn = (w & 1) << 6;
    f32x4 acc[2][4];
#pragma unroll
    for (int mi = 0; mi < 2; ++mi)
#pragma unroll
      for (int ni = 0; ni < 4; ++ni) acc[mi][ni] = (f32x4){0.f, 0.f, 0.f, 0.f};
    const int t2 = id - 1024;
    const int m0 = (t2 >> 5) * 64, n0 = (t2 & 31) * 128;
    const int srow = tid >> 3;
    const int gcol = ((tid & 7) ^ (srow & 7)) << 3;
    const u16* ag = Wt + 2048 * 1024 + (size_t)(m0 + srow) * 1024 + gcol;
    const u16* bg = xb + (size_t)(n0 + srow) * 1024 + gcol;
    u16* la = sA + w * 512;
    u16* lb = sB + w * 512;

    for (int k0 = 0; k0 < 1024; k0 += 64) {
      __syncthreads();
#pragma unroll
      for (int r = 0; r < 2; ++r) gld_lds16(ag + (size_t)r * 32 * 1024 + k0, la + r * 2048);
#pragma unroll
      for (int r = 0; r < 4; ++r) gld_lds16(bg + (size_t)r * 32 * 1024 + k0, lb + r * 2048);
      __syncthreads();
#pragma unroll
      for (int kk = 0; kk < 64; kk += 32) {
        const int c8 = (kk >> 3) + lq;
        bf16x8 af[2], bfr[4];
#pragma unroll
        for (int i = 0; i < 2; ++i) af[i] = ldsfrag(sA, wm + i * 16 + lr, c8);
#pragma unroll
        for (int i = 0; i < 4; ++i) bfr[i] = ldsfrag(sB, wn + i * 16 + lr, c8);
#pragma unroll
        for (int mi = 0; mi < 2; ++mi)
#pragma unroll
          for (int ni = 0; ni < 4; ++ni)
            acc[mi][ni] = __builtin_amdgcn_mfma_f32_16x16x32_bf16(af[mi], bfr[ni], acc[mi][ni], 0, 0, 0);
      }
    }
#pragma unroll
    for (int mi = 0; mi < 2; ++mi) {
      int gm = m0 + wm + mi * 16 + lq * 4;  // dv base
      float4 bv = *(const float4*)(bias + 2048 + gm);
#pragma unroll
      for (int ni = 0; ni < 4; ++ni) {
        int gn = n0 + wn + ni * 16 + lr;  // t (coalesced)
        int b = gn >> 11, tt = gn & 2047;
#pragma unroll
        for (int r = 0; r < 4; ++r) {
          int dv = gm + r;
          float v = acc[mi][ni][r] + ((const float*)&bv)[r];
          vtb[((size_t)(b * 1024 + dv)) * 2048 + tt] = f2bf(v);
        }
      }
    }
  }
}

// ---------------- flash attention v14: v12 loop + FUSED split-merge.
// After writing its partial, each side does threadfence -> atomicAdd(pflag[pi]);
// the SECOND finisher (old==1) re-fences and merges the two partials inline
// (exact k_merge math), eliminating the separate k_merge launch. No
// co-residency assumption: if one side retires before the other launches, the
// later one merges. Flags zeroed in k_prep (stream-ordered before attn).
#define TRIP(TT, SC, SN)                                                          \
  do {                                                                            \
    const int t = (TT);                                                           \
    __syncthreads();                                                              \
    if (t + 2 < NT) {                                                             \
      int j = t + 2;                                                              \
      int kv = isX ? ((j <= p) ? j : j - p - 1) : (kvY + j);                      \
      u16* lk = sK[t & 1] + w * 512;                                              \
      _Pragma("unroll") for (int r = 0; r < 2; ++r)                               \
          gld_lds16(kh + (size_t)(kv * 64 + r * 32 + srow) * 64 + gcol,           \
                    lk + r * 2048);                                               \
    }                                                                             \
    if (t + 1 < NT) {                                                             \
      int j = t + 1;                                                              \
      int kv = isX ? ((j <= p) ? j : j - p - 1) : (kvY + j);                      \
      u16* lv = sV[(t + 1) & 1] + w * 512;                                        \
      _Pragma("unroll") for (int r = 0; r < 2; ++r)                               \
          gld_lds16(vh + (size_t)(r * 32 + srow) * 2048 + kv * 64 + gcol,         \
                    lv + r * 2048);                                               \
    }                                                                             \
    if (t + 1 < NT) {                                                             \
      const u16* nK = sK[(t + 1) & 1];                                            \
      bf16x8 q0 = (t + 1 <= pSw) ? qa0 : qb0;                                     \
      bf16x8 q1 = (t + 1 <= pSw) ? qa1 : qb1;                                     \
      _Pragma("unroll") for (int nj = 0; nj < 4; ++nj) SN[nj] =                   \
          (f32x4){0.f, 0.f, 0.f, 0.f};                                            \
      __builtin_amdgcn_s_setprio(1);                                              \
      _Pragma("unroll") for (int kk = 0; kk < 64; kk += 32) {                     \
        const int c8 = (kk >> 3) + lq;                                            \
        bf16x8 kf[4];                                                             \
        _Pragma("unroll") for (int nj = 0; nj < 4; ++nj) kf[nj] =                 \
            ldsfrag(nK, nj * 16 + lr, c8);                                        \
        _Pragma("unroll") for (int nj = 0; nj < 4; ++nj) SN[nj] =                 \
            __builtin_amdgcn_mfma_f32_16x16x32_bf16(kf[nj], kk ? q1 : q0,         \
                                                    SN[nj], 0, 0, 0);             \
      }                                                                           \
      __builtin_amdgcn_s_setprio(0);                                              \
    }                                                                             \
    if (t == maskT) {                                                             \
      _Pragma("unroll") for (int nj = 0; nj < 4; ++nj)                            \
          _Pragma("unroll") for (int r = 0; r < 4; ++r) {                         \
        if (nj * 16 + lq * 4 + r > qloc) SC[nj][r] = -1e30f;                      \
      }                                                                           \
    }                                                                             \
    float mx = fmaxf(fmaxf(SC[0][0], SC[0][1]), fmaxf(SC[0][2], SC[0][3]));       \
    mx = fmaxf(mx, fmaxf(fmaxf(SC[1][0], SC[1][1]), fmaxf(SC[1][2], SC[1][3]))); \
    mx = fmaxf(mx, fmaxf(fmaxf(SC[2][0], SC[2][1]), fmaxf(SC[2][2], SC[2][3]))); \
    mx = fmaxf(mx, fmaxf(fmaxf(SC[3][0], SC[3][1]), fmaxf(SC[3][2], SC[3][3]))); \
    mx = fmaxf(mx, __shfl_xor(mx, 16));                                           \
    mx = fmaxf(mx, __shfl_xor(mx, 32));                                           \
    if (__any(mx > mL2 + 8.f)) {                                                  \
      float mn = fmaxf(mL2, mx);                                                  \
      float al = fexp2(mL2 - mn);                                                 \
      mL2 = mn;                                                                   \
      lrp *= al;                                                                  \
      _Pragma("unroll") for (int nj = 0; nj < 4; ++nj)                            \
          _Pragma("unroll") for (int r = 0; r < 4; ++r) o[nj][r] *= al;           \
    }                                                                             \
    {                                                                             \
      float rsA = 0.f, rsB = 0.f;                                                 \
      _Pragma("unroll") for (int nj = 0; nj < 4; ++nj) {                          \
        _Pragma("unroll") for (int r = 0; r < 4; ++r) SC[nj][r] =                 \
            fexp2(SC[nj][r] - mL2);                                               \
        float pa2 = (SC[nj][0] + SC[nj][1]) + (SC[nj][2] + SC[nj][3]);            \
        if (nj & 1) rsB += pa2; else rsA += pa2;                                  \
      }                                                                           \
      lrp += rsA + rsB;                                                           \
    }                                                                             \
    u32 pk0[4], pk1[4];                                                           \
    _Pragma("unroll") for (int nj = 0; nj < 4; ++nj) {                            \
      pk0[nj] = cvtpk_bf16(SC[nj][0], SC[nj][1]);                                 \
      pk1[nj] = cvtpk_bf16(SC[nj][2], SC[nj][3]);                                 \
    }                                                                             \
    u32 W000, W001, W010, W011, W100, W101, W110, W111;                           \
    {                                                                             \
      u32 v00 = bs0 ? pk0[1] : pk0[0];                                            \
      u32 v01 = bs0 ? pk1[1] : pk1[0];                                            \
      u32 v10 = bs0 ? pk0[0] : pk0[1];                                            \
      u32 v11 = bs0 ? pk1[0] : pk1[1];                                            \
      u32 r00 = (u32)__builtin_amdgcn_ds_bpermute(xadr0, (int)v00);               \
      u32 r01 = (u32)__builtin_amdgcn_ds_bpermute(xadr0, (int)v01);               \
      u32 r10 = (u32)__builtin_amdgcn_ds_bpermute(xadr1, (int)v10);               \
      u32 r11 = (u32)__builtin_amdgcn_ds_bpermute(xadr1, (int)v11);               \
      W000 = bd1 ? r10 : r00;                                                     \
      W001 = bd1 ? r11 : r01;                                                     \
      W010 = bd1 ? r00 : r10;                                                     \
      W011 = bd1 ? r01 : r11;                                                     \
      u32 u00 = bs0 ? pk0[3] : pk0[2];                                            \
      u32 u01 = bs0 ? pk1[3] : pk1[2];                                            \
      u32 u10 = bs0 ? pk0[2] : pk0[3];                                            \
      u32 u11 = bs0 ? pk1[2] : pk1[3];                                            \
      u32 t00 = (u32)__builtin_amdgcn_ds_bpermute(xadr0, (int)u00);               \
      u32 t01 = (u32)__builtin_amdgcn_ds_bpermute(xadr0, (int)u01);               \
      u32 t10 = (u32)__builtin_amdgcn_ds_bpermute(xadr1, (int)u10);               \
      u32 t11 = (u32)__builtin_amdgcn_ds_bpermute(xadr1, (int)u11);               \
      W100 = bd1 ? t10 : t00;                                                     \
      W101 = bd1 ? t11 : t01;                                                     \
      W110 = bd1 ? t00 : t10;                                                     \
      W111 = bd1 ? t01 : t11;                                                     \
    }                                                                             \
    union B8 { u32 u[4]; bf16x8 v; };                                             \
    B8 pb0u, pb1u;                                                                \
    pb0u.u[0] = W000; pb0u.u[1] = W001; pb0u.u[2] = W010; pb0u.u[3] = W011;       \
    pb1u.u[0] = W100; pb1u.u[1] = W101; pb1u.u[2] = W110; pb1u.u[3] = W111;       \
    {                                                                             \
      const u16* cV = sV[t & 1];                                                  \
      __builtin_amdgcn_s_setprio(1);                                              \
      _Pragma("unroll") for (int kkidx = 0; kkidx < 2; ++kkidx) {                 \
        const int c8 = kkidx * 4 + lq;                                            \
        bf16x8 pb = kkidx ? pb1u.v : pb0u.v;                                      \
        bf16x8 vf[4];                                                             \
        _Pragma("unroll") for (int nj = 0; nj < 4; ++nj) vf[nj] =                 \
            ldsfrag(cV, nj * 16 + lr, c8);                                        \
        _Pragma("unroll") for (int nj = 0; nj < 4; ++nj) o[nj] =                  \
            __builtin_amdgcn_mfma_f32_16x16x32_bf16(vf[nj], pb, o[nj], 0, 0, 0);  \
      }                                                                           \
      __builtin_amdgcn_s_setprio(0);                                              \
    }                                                                             \
    if (isX && t == p) {                                                          \
      float ls = lrp;                                                             \
      ls += __shfl_xor(ls, 16);                                                   \
      ls += __shfl_xor(ls, 32);                                                   \
      float inv = 1.0f / ls;                                                      \
      size_t base = ((size_t)(b * 2048 + (p << 6) + qloc)) * 1024 + h * 64;       \
      _Pragma("unroll") for (int nj = 0; nj < 4; ++nj) {                          \
        ushort4 sv;                                                               \
        sv.x = f2bf(o[nj][0] * inv);                                              \
        sv.y = f2bf(o[nj][1] * inv);                                              \
        sv.z = f2bf(o[nj][2] * inv);                                              \
        sv.w = f2bf(o[nj][3] * inv);                                              \
        *(ushort4*)(yb + base + nj * 16 + lq * 4) = sv;                           \
      }                                                                           \
      _Pragma("unroll") for (int j2 = 0; j2 < 4; ++j2) o[j2] =                    \
          (f32x4){0.f, 0.f, 0.f, 0.f};                                            \
      mL2 = -1e30f;                                                               \
      lrp = 0.f;                                                                  \
    }                                                                             \
  } while (0)

__global__ __launch_bounds__(256, 4) void k_attn(const u16* __restrict__ qbp,
                                                 const u16* __restrict__ kbp,
                                                 const u16* __restrict__ vtp,
                                                 u16* __restrict__ yb,
                                                 float* __restrict__ po,
                                                 float* __restrict__ pml,
                                                 u32* __restrict__ pflag) {
  __shared__ u16 sK[2][64 * 64];  // 16KB dbuf (stream pos i -> sK[i&1])
  __shared__ u16 sV[2][64 * 64];  // 16KB dbuf, [hd][kv]
  __shared__ int sOld;

  const int tid = threadIdx.x;
  const int lane = tid & 63, w = tid >> 6;
  const int lr = lane & 15, lq = lane >> 4;
  const int l = blockIdx.x;
  const int bh = l & 31;
  const int u = l >> 5;  // 0..31
  const bool isX = (u < 16);
  const int p = isX ? u : (u - 16);
  const int NT = isX ? 17 : 16;
  const int pSw = isX ? p : -1;    // stream pos <= pSw uses q-tile a
  const int maskT = isX ? p : 15;  // diagonal-mask trip
  const int kvY = 16 - p;          // Y: kv = kvY + t

  const u16* qh = qbp + (size_t)bh * (2048 * 64);
  const u16* kh = kbp + (size_t)bh * (2048 * 64);
  const u16* vh = vtp + (size_t)bh * (64 * 2048);

  // Q fragments (B-operand of swapped mfma; layout identical to A): lane q=lr
  bf16x8 qa0, qa1, qb0, qb1;
  {
    const u16* qpb = qh + (size_t)(((31 - p) << 6) + w * 16 + lr) * 64 + lq * 8;
    qb0 = *(const bf16x8*)(qpb);
    qb1 = *(const bf16x8*)(qpb + 32);
    if (isX) {
      const u16* qpa = qh + (size_t)((p << 6) + w * 16 + lr) * 64 + lq * 8;
      qa0 = *(const bf16x8*)(qpa);
      qa1 = *(const bf16x8*)(qpa + 32);
    } else {
      qa0 = qb0; qa1 = qb1;
    }
  }

  const int srow = tid >> 3;                       // 0..31
  const int gcol = ((tid & 7) ^ (srow & 7)) << 3;  // swizzled 16B chunk

  // bpermute addrs for the 4-lane (lq-group) exchange; partner has same lr
  const int xadr0 = 4 * (lr + 16 * (2 * (lq & 1) + (lq >> 1)));
  const int xadr1 = xadr0 ^ 64;
  const bool bs0 = (lq & 1) != 0;
  const bool bd1 = (lq >> 1) != 0;

  {  // prologue staging: K(stream0), K(stream1), V(stream0)
    const int kv0 = isX ? 0 : kvY;
    const int kv1 = isX ? ((1 <= p) ? 1 : 0) : (kvY + 1);
    u16* lk0 = sK[0] + w * 512;
    u16* lk1 = sK[1] + w * 512;
    u16* lv0 = sV[0] + w * 512;
#pragma unroll
    for (int r = 0; r < 2; ++r) {
      gld_lds16(kh + (size_t)(kv0 * 64 + r * 32 + srow) * 64 + gcol, lk0 + r * 2048);
      gld_lds16(vh + (size_t)(r * 32 + srow) * 2048 + kv0 * 64 + gcol, lv0 + r * 2048);
      gld_lds16(kh + (size_t)(kv1 * 64 + r * 32 + srow) * 64 + gcol, lk1 + r * 2048);
    }
  }
  __syncthreads();

  // S^T(stream 0) = K(0) Q^T : sA_[nj][r] = S^T[kv = nj*16+lq*4+r][q = lr]
  f32x4 sA_[4], sB_[4];
#pragma unroll
  for (int nj = 0; nj < 4; ++nj) sA_[nj] = (f32x4){0.f, 0.f, 0.f, 0.f};
  {
    bf16x8 q0 = (0 <= pSw) ? qa0 : qb0;
    bf16x8 q1 = (0 <= pSw) ? qa1 : qb1;
#pragma unroll
    for (int kk = 0; kk < 64; kk += 32) {
      const int c8 = (kk >> 3) + lq;
      bf16x8 kf[4];
#pragma unroll
      for (int nj = 0; nj < 4; ++nj) kf[nj] = ldsfrag(sK[0], nj * 16 + lr, c8);
#pragma unroll
      for (int nj = 0; nj < 4; ++nj)
        sA_[nj] = __builtin_amdgcn_mfma_f32_16x16x32_bf16(kf[nj], kk ? q1 : q0, sA_[nj], 0, 0, 0);
    }
  }

  f32x4 o[4];  // O^T: o[nj][r] = O^T[dv = nj*16+lq*4+r][q = lr]
  float mL2 = -1e30f, lrp = 0.f;  // per-lane scalars (one q per lane)
#pragma unroll
  for (int j = 0; j < 4; ++j) o[j] = (f32x4){0.f, 0.f, 0.f, 0.f};

  const int b = bh >> 4, h = bh & 15;
  const int qloc = w * 16 + lr;  // in-tile q row of this lane

  // 8 full pairs (t=0..15 valid for both NT=16 and NT=17)
  for (int tb = 0; tb < 8; ++tb) {
    TRIP(tb * 2, sA_, sB_);
    TRIP(tb * 2 + 1, sB_, sA_);
  }
  if (NT == 17) TRIP(16, sA_, sB_);

  // partial write for q-tile b portion: side 0 = X prefix, side 1 = Y suffix
  const int pi = bh * 16 + p;
  {
    const int S = isX ? 0 : 1;
    float* poo = po + (size_t)(pi * 2 + S) * 4096;
    float* pmm = pml + (size_t)(pi * 2 + S) * 128;
    float ls = lrp;
    ls += __shfl_xor(ls, 16);
    ls += __shfl_xor(ls, 32);
    if (lq == 0) {
      float2 ml; ml.x = mL2; ml.y = ls;
      *(float2*)(pmm + qloc * 2) = ml;
    }
#pragma unroll
    for (int nj = 0; nj < 4; ++nj)
      *(f32x4*)(poo + qloc * 64 + nj * 16 + lq * 4) = o[nj];
  }

  // fused split-merge: second finisher per pi merges X/Y partials into ybuf.
  __threadfence();    // make this block's po/pml writes device-visible
  __syncthreads();    // all threads' stores + fences precede the flag bump
  if (tid == 0) sOld = (int)atomicAdd(&pflag[pi], 1u);
  __syncthreads();
  if (sOld == 1) {
    __threadfence();  // acquire: observe the other side's po/pml writes
    const int q0m = (31 - p) << 6;
    const float* oX = po + (size_t)(pi * 2 + 0) * 4096;
    const float* oY = po + (size_t)(pi * 2 + 1) * 4096;
    const float* mlX = pml + (size_t)(pi * 2 + 0) * 128;
    const float* mlY = pml + (size_t)(pi * 2 + 1) * 128;
#pragma unroll
    for (int k = 0; k < 16; ++k) {
      int idx = k * 256 + tid;
      int row = idx >> 6, col = idx & 63;
      float mX = mlX[row * 2], lX = mlX[row * 2 + 1];
      float mY = mlY[row * 2], lY = mlY[row * 2 + 1];
      float m = fmaxf(mX, mY);
      float aX = fexp2(mX - m), aY = fexp2(mY - m);
      float linv = 1.0f / (lX * aX + lY * aY);
      float y = (oX[idx] * aX + oY[idx] * aY) * linv;
      yb[((size_t)(b * 2048 + q0m + row)) * 1024 + h * 64 + col] = f2bf(y);
    }
  }
}

// ---------------- GEMM2: R4 verbatim. out = y @ W_proj + b, 64x64 tiles,
// dim3(16,64) grid = 4/CU ----------------
__global__ __launch_bounds__(256) void k_gemm_proj(const u16* __restrict__ ybuf,
                                                   const u16* __restrict__ Wt,
                                                   const float* __restrict__ bias,
                                                   float* __restrict__ out) {
  __shared__ u16 sA[64 * 64], sB[64 * 64];  // 16KB
  f32x4 acc[2][2];
#pragma unroll
  for (int mi = 0; mi < 2; ++mi)
#pragma unroll
    for (int ni = 0; ni < 2; ++ni) acc[mi][ni] = (f32x4){0.f, 0.f, 0.f, 0.f};

  const int m0 = blockIdx.y * 64, n0 = blockIdx.x * 64;
  const int tid = threadIdx.x;
  const int lane = tid & 63, w = tid >> 6;
  const int wm = (w >> 1) << 5, wn = (w & 1) << 5;  // wave tile 32x32
  const int lr = lane & 15, lq = lane >> 4;
  const int srow = tid >> 3;
  const int gcol = ((tid & 7) ^ (srow & 7)) << 3;
  const u16* ag = ybuf + (size_t)(m0 + srow) * 1024 + gcol;
  const u16* bg = Wt + (size_t)(n0 + srow) * 1024 + gcol;
  u16* la = sA + w * 512;
  u16* lb = sB + w * 512;

  for (int k0 = 0; k0 < 1024; k0 += 64) {
    __syncthreads();
#pragma unroll
    for (int r = 0; r < 2; ++r) {
      gld_lds16(ag + (size_t)r * 32 * 1024 + k0, la + r * 2048);
      gld_lds16(bg + (size_t)r * 32 * 1024 + k0, lb + r * 2048);
    }
    __syncthreads();
#pragma unroll
    for (int kk = 0; kk < 64; kk += 32) {
      const int c8 = (kk >> 3) + lq;
      bf16x8 af[2], bfr[2];
#pragma unroll
      for (int i = 0; i < 2; ++i) {
        af[i] = ldsfrag(sA, wm + i * 16 + lr, c8);
        bfr[i] = ldsfrag(sB, wn + i * 16 + lr, c8);
      }
#pragma unroll
      for (int mi = 0; mi < 2; ++mi)
#pragma unroll
        for (int ni = 0; ni < 2; ++ni)
          acc[mi][ni] = __builtin_amdgcn_mfma_f32_16x16x32_bf16(af[mi], bfr[ni], acc[mi][ni], 0, 0, 0);
    }
  }

#pragma unroll
  for (int mi = 0; mi < 2; ++mi) {
    int gm = m0 + wm + mi * 16 + lq * 4;
#pragma unroll
    for (int ni = 0; ni < 2; ++ni) {
      int gn = n0 + wn + ni * 16 + lr;
      float bv = bias[gn];
#pragma unroll
      for (int r = 0; r < 4; ++r) out[(size_t)(gm + r) * 1024 + gn] = acc[mi][ni][r] + bv;
    }
  }
}

extern "C" void kernel_launch(void* const* d_in, const int* in_sizes, int n_in,
                              void* d_out, int out_size, void* d_ws, size_t ws_size,
                              hipStream_t stream) {
  const float* x = (const float*)d_in[0];       // [2,2048,1024]
  const float* W_attn = (const float*)d_in[1];  // [1024,3072]
  const float* b_attn = (const float*)d_in[2];  // [3072]
  const float* W_proj = (const float*)d_in[3];  // [1024,1024]
  const float* b_proj = (const float*)d_in[4];  // [1024]
  float* out = (float*)d_out;                   // [2,2048,1024] fp32

  u16* ws = (u16*)d_ws;
  u16* xb = ws;                   // 4096x1024 bf16          bytes [0, 8388608)
  u16* WaT = ws + 4194304;        // 3072x1024 (rows 2048.. used)  [8388608, 14680064)
  u16* qbuf = ws + 8388608;       // [32][2048][64]           [16777216, 25165824)
  u16* kbuf = ws + 12582912;      // [32][2048][64]           [25165824, 33554432)
  u16* vtb = ws + 16777216;       // [32][64][2048]           [33554432, 41943040)
  u16* ybuf = ws + 20971520;      // [4096][1024]             [41943040, 50331648)
  s8* xq = (s8*)ybuf;             // 4096x1024 i8 (aliases ybuf, dead until attn)
  s8* wq8 = (s8*)ybuf + 4194304;  // 2048x1024 i8
  float* po = (float*)ws;         // 512x2x4096 f32 partial O, aliases xb/WaT
                                  //   (dead after k_gemm_qkv): bytes [0, 16777216)
  float* pml = (float*)(ws + 25165824);  // 512x2x128 f32 (m,l) [50331648, 50855936)
  u16* WpT = ws + 25427968;       // 1024x1024 W_proj^T        [50855936, 52953088)
  u32* pflag = (u32*)(ws + 26476544);    // 512 u32 completion flags [52953088, 52955136)

  k_prep<<<dim3(3072), dim3(256), 0, stream>>>(x, xb, xq, W_attn, WaT, wq8, W_proj, WpT, pflag);
  k_gemm_qkv<<<dim3(1536), dim3(256), 0, stream>>>(xb, xq, WaT, wq8, b_attn, qbuf, kbuf, vtb);
  k_attn<<<dim3(1024), dim3(256), 0, stream>>>(qbuf, kbuf, vtb, ybuf, po, pml, pflag);
  k_gemm_proj<<<dim3(16, 64), dim3(256), 0, stream>>>(ybuf, WpT, b_proj, out);
}

// Round 11
// 172.285 us; speedup vs baseline: 2.0894x; 2.0894x over previous
//
#include <hip/hip_runtime.h>

typedef unsigned short u16;
typedef unsigned char u8;
typedef signed char s8;
typedef unsigned int u32;
typedef short bf16x8 __attribute__((ext_vector_type(8)));
typedef float f32x4 __attribute__((ext_vector_type(4)));
typedef int i32x4 __attribute__((ext_vector_type(4)));

#define SXI 21.1666667f     /* 127/6.0  : x quant */
#define SWI 1058.3333f      /* 127/0.12 : W quant */
#define DEQ 4.4640015e-5f   /* (6.0*0.12)/(127*127) */

__device__ __forceinline__ u16 f2bf(float f) {
  union { float f; u32 u; } v; v.f = f;
  u32 r = v.u + 0x7fffu + ((v.u >> 16) & 1u);
  return (u16)(r >> 16);
}
__device__ __forceinline__ s8 q8(float v, float s) {
  float x = fminf(127.f, fmaxf(-127.f, v * s));
  return (s8)__float2int_rn(x);
}
__device__ __forceinline__ float fexp2(float x) {
#if __has_builtin(__builtin_amdgcn_exp2f)
  return __builtin_amdgcn_exp2f(x);
#else
  return exp2f(x);
#endif
}
__device__ __forceinline__ u32 cvtpk_bf16(float lo, float hi) {
  u32 r;
  asm("v_cvt_pk_bf16_f32 %0, %1, %2" : "=v"(r) : "v"(lo), "v"(hi));
  return r;
}

__device__ __forceinline__ void gld_lds16(const u16* g, u16* l) {
  __builtin_amdgcn_global_load_lds(
      (__attribute__((address_space(1))) u32*)(g),
      (__attribute__((address_space(3))) u32*)(l), 16, 0, 0);
}
__device__ __forceinline__ void gld_lds16b(const u8* g, u8* l) {
  __builtin_amdgcn_global_load_lds(
      (__attribute__((address_space(1))) u32*)(g),
      (__attribute__((address_space(3))) u32*)(l), 16, 0, 0);
}

// bf16 tiles: rows of 64 bf16 = 8 x 16B chunks, phys chunk = c ^ (row&7)
__device__ __forceinline__ bf16x8 ldsfrag(const u16* base, int row, int c8) {
  return *(const bf16x8*)(base + row * 64 + ((c8 ^ (row & 7)) << 3));
}
// i8 tiles: rows of 64 i8 = 4 x 16B chunks, phys chunk = c ^ swz4(row)
__device__ __forceinline__ int swz4(int r) { return (r & 3) ^ ((r >> 2) & 3); }

// ---------------- prep: x->bf16+i8, W_attn^T (qk i8, v bf16), W_proj^T ----------------
__global__ __launch_bounds__(256) void k_prep(const float* __restrict__ x, u16* __restrict__ xb,
                                              s8* __restrict__ xq,
                                              const float* __restrict__ Wa, u16* __restrict__ WaT,
                                              s8* __restrict__ wq8,
                                              const float* __restrict__ Wp, u16* __restrict__ WpT) {
  __shared__ float t[64][65];
  const int id = blockIdx.x;
  if (id < 2048) {
    int i = (id * 256 + threadIdx.x) * 8;
    const float4* p = (const float4*)(x + i);
    float4 a = p[0], b = p[1];
    uint4 o;
    o.x = (u32)f2bf(a.x) | ((u32)f2bf(a.y) << 16);
    o.y = (u32)f2bf(a.z) | ((u32)f2bf(a.w) << 16);
    o.z = (u32)f2bf(b.x) | ((u32)f2bf(b.y) << 16);
    o.w = (u32)f2bf(b.z) | ((u32)f2bf(b.w) << 16);
    *(uint4*)(xb + i) = o;
    u32 lo = (u32)(u8)q8(a.x, SXI) | ((u32)(u8)q8(a.y, SXI) << 8) |
             ((u32)(u8)q8(a.z, SXI) << 16) | ((u32)(u8)q8(a.w, SXI) << 24);
    u32 hi = (u32)(u8)q8(b.x, SXI) | ((u32)(u8)q8(b.y, SXI) << 8) |
             ((u32)(u8)q8(b.z, SXI) << 16) | ((u32)(u8)q8(b.w, SXI) << 24);
    uint2 oq; oq.x = lo; oq.y = hi;
    *(uint2*)(xq + i) = oq;
  } else if (id < 2816) {
    int q = id - 2048;
    int bx = q % 48, by = q / 48;
    int c0 = bx * 64, r0 = by * 64;
    int tx = threadIdx.x & 63, ty = threadIdx.x >> 6;
#pragma unroll
    for (int i = ty; i < 64; i += 4) t[i][tx] = Wa[(size_t)(r0 + i) * 3072 + c0 + tx];
    __syncthreads();
#pragma unroll
    for (int i = ty; i < 64; i += 4) {
      int row = c0 + i;
      if (row < 2048)
        wq8[(size_t)row * 1024 + r0 + tx] = q8(t[tx][i], SWI);
      else
        WaT[(size_t)row * 1024 + r0 + tx] = f2bf(t[tx][i]);
    }
  } else {
    int q = id - 2816;
    int bx = q & 15, by = q >> 4;
    int c0 = bx * 64, r0 = by * 64;
    int tx = threadIdx.x & 63, ty = threadIdx.x >> 6;
#pragma unroll
    for (int i = ty; i < 64; i += 4) t[i][tx] = Wp[(size_t)(r0 + i) * 1024 + c0 + tx];
    __syncthreads();
#pragma unroll
    for (int i = ty; i < 64; i += 4)
      WpT[(size_t)(c0 + i) * 1024 + r0 + tx] = f2bf(t[tx][i]);
  }
}

// ---------------- GEMM1: R4 verbatim (64x128 tiles, 1536 blocks, 6/CU, BK=64) ----------------
__global__ __launch_bounds__(256) void k_gemm_qkv(const u16* __restrict__ xb,
                                                  const s8* __restrict__ xq,
                                                  const u16* __restrict__ Wt,
                                                  const s8* __restrict__ wq8,
                                                  const float* __restrict__ bias,
                                                  u16* __restrict__ qb, u16* __restrict__ kb,
                                                  u16* __restrict__ vtb) {
  const int id = blockIdx.x;
  const int tid = threadIdx.x;
  const int lane = tid & 63, w = tid >> 6;
  const int lr = lane & 15, lq = lane >> 4;

  if (id < 1024) {
    // ---- int8 qk: 64x128 tile. C[t][n], n in [0,2048) ----
    __shared__ __align__(16) u8 la8[64 * 64], lb8[128 * 64];  // 12KB
    const int wm = (w >> 1) << 5, wn = (w & 1) << 6;
    i32x4 acc[2][4];
#pragma unroll
    for (int mi = 0; mi < 2; ++mi)
#pragma unroll
      for (int ni = 0; ni < 4; ++ni) acc[mi][ni] = (i32x4){0, 0, 0, 0};
    const int m0 = (id >> 4) * 64, n0 = (id & 15) * 128;
    const int srow4 = tid >> 2;  // 0..63
    const int gcol4 = (((tid & 3) ^ swz4(srow4)) << 4);
    const u8* ag = (const u8*)xq + (size_t)(m0 + srow4) * 1024 + gcol4;
    const u8* bg = (const u8*)wq8 + (size_t)(n0 + srow4) * 1024 + gcol4;

    for (int k0 = 0; k0 < 1024; k0 += 64) {
      __syncthreads();
      gld_lds16b(ag + k0, la8 + (w * 16) * 64);
#pragma unroll
      for (int r = 0; r < 2; ++r)
        gld_lds16b(bg + (size_t)r * 64 * 1024 + k0, lb8 + (r * 64 + w * 16) * 64);
      __syncthreads();
      i32x4 a[2], b[4];
#pragma unroll
      for (int mi = 0; mi < 2; ++mi) {
        int m = wm + mi * 16 + lr;
        a[mi] = *(const i32x4*)(la8 + m * 64 + ((lq ^ swz4(m)) << 4));
      }
#pragma unroll
      for (int ni = 0; ni < 4; ++ni) {
        int n = wn + ni * 16 + lr;
        b[ni] = *(const i32x4*)(lb8 + n * 64 + ((lq ^ swz4(n)) << 4));
      }
#pragma unroll
      for (int mi = 0; mi < 2; ++mi)
#pragma unroll
        for (int ni = 0; ni < 4; ++ni)
          acc[mi][ni] = __builtin_amdgcn_mfma_i32_16x16x64_i8(a[mi], b[ni], acc[mi][ni], 0, 0, 0);
    }
#pragma unroll
    for (int mi = 0; mi < 2; ++mi) {
      int gm = m0 + wm + mi * 16 + lq * 4;
#pragma unroll
      for (int ni = 0; ni < 4; ++ni) {
        int gn = n0 + wn + ni * 16 + lr;
        float bv = bias[gn];
        int which = gn >> 10, head = (gn >> 6) & 15, hd = gn & 63;
#pragma unroll
        for (int r = 0; r < 4; ++r) {
          int row = gm + r;
          int b2 = row >> 11, tt = row & 2047;
          float v = (float)acc[mi][ni][r] * DEQ + bv;
          size_t bh = (size_t)(b2 * 16 + head);
          if (which == 0)
            qb[(bh * 2048 + tt) * 64 + hd] = f2bf(v * 0.18033688f);  // fold 1/sqrt(64)*log2(e)
          else
            kb[(bh * 2048 + tt) * 64 + hd] = f2bf(v);
        }
      }
    }
  } else {
    // ---- bf16 v^T: 64x128 tile. A = WaT rows 2048.. (M=1024=dv), Bt = xb (N=4096=t) ----
    __shared__ u16 sA[64 * 64], sB[128 * 64];  // 24KB
    const int wm = (w >> 1) << 5, wn = (w & 1) << 6;
    f32x4 acc[2][4];
#pragma unroll
    for (int mi = 0; mi < 2; ++mi)
#pragma unroll
      for (int ni = 0; ni < 4; ++ni) acc[mi][ni] = (f32x4){0.f, 0.f, 0.f, 0.f};
    const int t2 = id - 1024;
    const int m0 = (t2 >> 5) * 64, n0 = (t2 & 31) * 128;
    const int srow = tid >> 3;
    const int gcol = ((tid & 7) ^ (srow & 7)) << 3;
    const u16* ag = Wt + 2048 * 1024 + (size_t)(m0 + srow) * 1024 + gcol;
    const u16* bg = xb + (size_t)(n0 + srow) * 1024 + gcol;
    u16* la = sA + w * 512;
    u16* lb = sB + w * 512;

    for (int k0 = 0; k0 < 1024; k0 += 64) {
      __syncthreads();
#pragma unroll
      for (int r = 0; r < 2; ++r) gld_lds16(ag + (size_t)r * 32 * 1024 + k0, la + r * 2048);
#pragma unroll
      for (int r = 0; r < 4; ++r) gld_lds16(bg + (size_t)r * 32 * 1024 + k0, lb + r * 2048);
      __syncthreads();
#pragma unroll
      for (int kk = 0; kk < 64; kk += 32) {
        const int c8 = (kk >> 3) + lq;
        bf16x8 af[2], bfr[4];
#pragma unroll
        for (int i = 0; i < 2; ++i) af[i] = ldsfrag(sA, wm + i * 16 + lr, c8);
#pragma unroll
        for (int i = 0; i < 4; ++i) bfr[i] = ldsfrag(sB, wn + i * 16 + lr, c8);
#pragma unroll
        for (int mi = 0; mi < 2; ++mi)
#pragma unroll
          for (int ni = 0; ni < 4; ++ni)
            acc[mi][ni] = __builtin_amdgcn_mfma_f32_16x16x32_bf16(af[mi], bfr[ni], acc[mi][ni], 0, 0, 0);
      }
    }
#pragma unroll
    for (int mi = 0; mi < 2; ++mi) {
      int gm = m0 + wm + mi * 16 + lq * 4;  // dv base
      float4 bv = *(const float4*)(bias + 2048 + gm);
#pragma unroll
      for (int ni = 0; ni < 4; ++ni) {
        int gn = n0 + wn + ni * 16 + lr;  // t (coalesced)
        int b = gn >> 11, tt = gn & 2047;
#pragma unroll
        for (int r = 0; r < 4; ++r) {
          int dv = gm + r;
          float v = acc[mi][ni][r] + ((const float*)&bv)[r];
          vtb[((size_t)(b * 1024 + dv)) * 2048 + tt] = f2bf(v);
        }
      }
    }
  }
}

// ---------------- flash attention v12 (best measured, 41.7us): swapped QK^T,
// in-register P exchange, uniform-trip kv-split grid, setprio MFMA clusters,
// unroll-2 S/Sn ping-pong, tree-summed lrp. Separate k_merge (fused-merge's
// per-block device fence thrashed L2: 240us, R9).
#define TRIP(TT, SC, SN)                                                          \
  do {                                                                            \
    const int t = (TT);                                                           \
    __syncthreads();                                                              \
    if (t + 2 < NT) {                                                             \
      int j = t + 2;                                                              \
      int kv = isX ? ((j <= p) ? j : j - p - 1) : (kvY + j);                      \
      u16* lk = sK[t & 1] + w * 512;                                              \
      _Pragma("unroll") for (int r = 0; r < 2; ++r)                               \
          gld_lds16(kh + (size_t)(kv * 64 + r * 32 + srow) * 64 + gcol,           \
                    lk + r * 2048);                                               \
    }                                                                             \
    if (t + 1 < NT) {                                                             \
      int j = t + 1;                                                              \
      int kv = isX ? ((j <= p) ? j : j - p - 1) : (kvY + j);                      \
      u16* lv = sV[(t + 1) & 1] + w * 512;                                        \
      _Pragma("unroll") for (int r = 0; r < 2; ++r)                               \
          gld_lds16(vh + (size_t)(r * 32 + srow) * 2048 + kv * 64 + gcol,         \
                    lv + r * 2048);                                               \
    }                                                                             \
    if (t + 1 < NT) {                                                             \
      const u16* nK = sK[(t + 1) & 1];                                            \
      bf16x8 q0 = (t + 1 <= pSw) ? qa0 : qb0;                                     \
      bf16x8 q1 = (t + 1 <= pSw) ? qa1 : qb1;                                     \
      _Pragma("unroll") for (int nj = 0; nj < 4; ++nj) SN[nj] =                   \
          (f32x4){0.f, 0.f, 0.f, 0.f};                                            \
      __builtin_amdgcn_s_setprio(1);                                              \
      _Pragma("unroll") for (int kk = 0; kk < 64; kk += 32) {                     \
        const int c8 = (kk >> 3) + lq;                                            \
        bf16x8 kf[4];                                                             \
        _Pragma("unroll") for (int nj = 0; nj < 4; ++nj) kf[nj] =                 \
            ldsfrag(nK, nj * 16 + lr, c8);                                        \
        _Pragma("unroll") for (int nj = 0; nj < 4; ++nj) SN[nj] =                 \
            __builtin_amdgcn_mfma_f32_16x16x32_bf16(kf[nj], kk ? q1 : q0,         \
                                                    SN[nj], 0, 0, 0);             \
      }                                                                           \
      __builtin_amdgcn_s_setprio(0);                                              \
    }                                                                             \
    if (t == maskT) {                                                             \
      _Pragma("unroll") for (int nj = 0; nj < 4; ++nj)                            \
          _Pragma("unroll") for (int r = 0; r < 4; ++r) {                         \
        if (nj * 16 + lq * 4 + r > qloc) SC[nj][r] = -1e30f;                      \
      }                                                                           \
    }                                                                             \
    float mx = fmaxf(fmaxf(SC[0][0], SC[0][1]), fmaxf(SC[0][2], SC[0][3]));       \
    mx = fmaxf(mx, fmaxf(fmaxf(SC[1][0], SC[1][1]), fmaxf(SC[1][2], SC[1][3]))); \
    mx = fmaxf(mx, fmaxf(fmaxf(SC[2][0], SC[2][1]), fmaxf(SC[2][2], SC[2][3]))); \
    mx = fmaxf(mx, fmaxf(fmaxf(SC[3][0], SC[3][1]), fmaxf(SC[3][2], SC[3][3]))); \
    mx = fmaxf(mx, __shfl_xor(mx, 16));                                           \
    mx = fmaxf(mx, __shfl_xor(mx, 32));                                           \
    if (__any(mx > mL2 + 8.f)) {                                                  \
      float mn = fmaxf(mL2, mx);                                                  \
      float al = fexp2(mL2 - mn);                                                 \
      mL2 = mn;                                                                   \
      lrp *= al;                                                                  \
      _Pragma("unroll") for (int nj = 0; nj < 4; ++nj)                            \
          _Pragma("unroll") for (int r = 0; r < 4; ++r) o[nj][r] *= al;           \
    }                                                                             \
    {                                                                             \
      float rsA = 0.f, rsB = 0.f;                                                 \
      _Pragma("unroll") for (int nj = 0; nj < 4; ++nj) {                          \
        _Pragma("unroll") for (int r = 0; r < 4; ++r) SC[nj][r] =                 \
            fexp2(SC[nj][r] - mL2);                                               \
        float pa2 = (SC[nj][0] + SC[nj][1]) + (SC[nj][2] + SC[nj][3]);            \
        if (nj & 1) rsB += pa2; else rsA += pa2;                                  \
      }                                                                           \
      lrp += rsA + rsB;                                                           \
    }                                                                             \
    u32 pk0[4], pk1[4];                                                           \
    _Pragma("unroll") for (int nj = 0; nj < 4; ++nj) {                            \
      pk0[nj] = cvtpk_bf16(SC[nj][0], SC[nj][1]);                                 \
      pk1[nj] = cvtpk_bf16(SC[nj][2], SC[nj][3]);                                 \
    }                                                                             \
    u32 W000, W001, W010, W011, W100, W101, W110, W111;                           \
    {                                                                             \
      u32 v00 = bs0 ? pk0[1] : pk0[0];                                            \
      u32 v01 = bs0 ? pk1[1] : pk1[0];                                            \
      u32 v10 = bs0 ? pk0[0] : pk0[1];                                            \
      u32 v11 = bs0 ? pk1[0] : pk1[1];                                            \
      u32 r00 = (u32)__builtin_amdgcn_ds_bpermute(xadr0, (int)v00);               \
      u32 r01 = (u32)__builtin_amdgcn_ds_bpermute(xadr0, (int)v01);               \
      u32 r10 = (u32)__builtin_amdgcn_ds_bpermute(xadr1, (int)v10);               \
      u32 r11 = (u32)__builtin_amdgcn_ds_bpermute(xadr1, (int)v11);               \
      W000 = bd1 ? r10 : r00;                                                     \
      W001 = bd1 ? r11 : r01;                                                     \
      W010 = bd1 ? r00 : r10;                                                     \
      W011 = bd1 ? r01 : r11;                                                     \
      u32 u00 = bs0 ? pk0[3] : pk0[2];                                            \
      u32 u01 = bs0 ? pk1[3] : pk1[2];                                            \
      u32 u10 = bs0 ? pk0[2] : pk0[3];                                            \
      u32 u11 = bs0 ? pk1[2] : pk1[3];                                            \
      u32 t00 = (u32)__builtin_amdgcn_ds_bpermute(xadr0, (int)u00);               \
      u32 t01 = (u32)__builtin_amdgcn_ds_bpermute(xadr0, (int)u01);               \
      u32 t10 = (u32)__builtin_amdgcn_ds_bpermute(xadr1, (int)u10);               \
      u32 t11 = (u32)__builtin_amdgcn_ds_bpermute(xadr1, (int)u11);               \
      W100 = bd1 ? t10 : t00;                                                     \
      W101 = bd1 ? t11 : t01;                                                     \
      W110 = bd1 ? t00 : t10;                                                     \
      W111 = bd1 ? t01 : t11;                                                     \
    }                                                                             \
    union B8 { u32 u[4]; bf16x8 v; };                                             \
    B8 pb0u, pb1u;                                                                \
    pb0u.u[0] = W000; pb0u.u[1] = W001; pb0u.u[2] = W010; pb0u.u[3] = W011;       \
    pb1u.u[0] = W100; pb1u.u[1] = W101; pb1u.u[2] = W110; pb1u.u[3] = W111;       \
    {                                                                             \
      const u16* cV = sV[t & 1];                                                  \
      __builtin_amdgcn_s_setprio(1);                                              \
      _Pragma("unroll") for (int kkidx = 0; kkidx < 2; ++kkidx) {                 \
        const int c8 = kkidx * 4 + lq;                                            \
        bf16x8 pb = kkidx ? pb1u.v : pb0u.v;                                      \
        bf16x8 vf[4];                                                             \
        _Pragma("unroll") for (int nj = 0; nj < 4; ++nj) vf[nj] =                 \
            ldsfrag(cV, nj * 16 + lr, c8);                                        \
        _Pragma("unroll") for (int nj = 0; nj < 4; ++nj) o[nj] =                  \
            __builtin_amdgcn_mfma_f32_16x16x32_bf16(vf[nj], pb, o[nj], 0, 0, 0);  \
      }                                                                           \
      __builtin_amdgcn_s_setprio(0);                                              \
    }                                                                             \
    if (isX && t == p) {                                                          \
      float ls = lrp;                                                             \
      ls += __shfl_xor(ls, 16);                                                   \
      ls += __shfl_xor(ls, 32);                                                   \
      float inv = 1.0f / ls;                                                      \
      size_t base = ((size_t)(b * 2048 + (p << 6) + qloc)) * 1024 + h * 64;       \
      _Pragma("unroll") for (int nj = 0; nj < 4; ++nj) {                          \
        ushort4 sv;                                                               \
        sv.x = f2bf(o[nj][0] * inv);                                              \
        sv.y = f2bf(o[nj][1] * inv);                                              \
        sv.z = f2bf(o[nj][2] * inv);                                              \
        sv.w = f2bf(o[nj][3] * inv);                                              \
        *(ushort4*)(yb + base + nj * 16 + lq * 4) = sv;                           \
      }                                                                           \
      _Pragma("unroll") for (int j2 = 0; j2 < 4; ++j2) o[j2] =                    \
          (f32x4){0.f, 0.f, 0.f, 0.f};                                            \
      mL2 = -1e30f;                                                               \
      lrp = 0.f;                                                                  \
    }                                                                             \
  } while (0)

__global__ __launch_bounds__(256, 4) void k_attn(const u16* __restrict__ qbp,
                                                 const u16* __restrict__ kbp,
                                                 const u16* __restrict__ vtp,
                                                 u16* __restrict__ yb,
                                                 float* __restrict__ po,
                                                 float* __restrict__ pml) {
  __shared__ u16 sK[2][64 * 64];  // 16KB dbuf (stream pos i -> sK[i&1])
  __shared__ u16 sV[2][64 * 64];  // 16KB dbuf, [hd][kv]

  const int tid = threadIdx.x;
  const int lane = tid & 63, w = tid >> 6;
  const int lr = lane & 15, lq = lane >> 4;
  const int l = blockIdx.x;
  const int bh = l & 31;
  const int u = l >> 5;  // 0..31
  const bool isX = (u < 16);
  const int p = isX ? u : (u - 16);
  const int NT = isX ? 17 : 16;
  const int pSw = isX ? p : -1;    // stream pos <= pSw uses q-tile a
  const int maskT = isX ? p : 15;  // diagonal-mask trip
  const int kvY = 16 - p;          // Y: kv = kvY + t

  const u16* qh = qbp + (size_t)bh * (2048 * 64);
  const u16* kh = kbp + (size_t)bh * (2048 * 64);
  const u16* vh = vtp + (size_t)bh * (64 * 2048);

  // Q fragments (B-operand of swapped mfma; layout identical to A): lane q=lr
  bf16x8 qa0, qa1, qb0, qb1;
  {
    const u16* qpb = qh + (size_t)(((31 - p) << 6) + w * 16 + lr) * 64 + lq * 8;
    qb0 = *(const bf16x8*)(qpb);
    qb1 = *(const bf16x8*)(qpb + 32);
    if (isX) {
      const u16* qpa = qh + (size_t)((p << 6) + w * 16 + lr) * 64 + lq * 8;
      qa0 = *(const bf16x8*)(qpa);
      qa1 = *(const bf16x8*)(qpa + 32);
    } else {
      qa0 = qb0; qa1 = qb1;
    }
  }

  const int srow = tid >> 3;                       // 0..31
  const int gcol = ((tid & 7) ^ (srow & 7)) << 3;  // swizzled 16B chunk

  // bpermute addrs for the 4-lane (lq-group) exchange; partner has same lr
  const int xadr0 = 4 * (lr + 16 * (2 * (lq & 1) + (lq >> 1)));
  const int xadr1 = xadr0 ^ 64;
  const bool bs0 = (lq & 1) != 0;
  const bool bd1 = (lq >> 1) != 0;

  {  // prologue staging: K(stream0), K(stream1), V(stream0)
    const int kv0 = isX ? 0 : kvY;
    const int kv1 = isX ? ((1 <= p) ? 1 : 0) : (kvY + 1);
    u16* lk0 = sK[0] + w * 512;
    u16* lk1 = sK[1] + w * 512;
    u16* lv0 = sV[0] + w * 512;
#pragma unroll
    for (int r = 0; r < 2; ++r) {
      gld_lds16(kh + (size_t)(kv0 * 64 + r * 32 + srow) * 64 + gcol, lk0 + r * 2048);
      gld_lds16(vh + (size_t)(r * 32 + srow) * 2048 + kv0 * 64 + gcol, lv0 + r * 2048);
      gld_lds16(kh + (size_t)(kv1 * 64 + r * 32 + srow) * 64 + gcol, lk1 + r * 2048);
    }
  }
  __syncthreads();

  // S^T(stream 0) = K(0) Q^T : sA_[nj][r] = S^T[kv = nj*16+lq*4+r][q = lr]
  f32x4 sA_[4], sB_[4];
#pragma unroll
  for (int nj = 0; nj < 4; ++nj) sA_[nj] = (f32x4){0.f, 0.f, 0.f, 0.f};
  {
    bf16x8 q0 = (0 <= pSw) ? qa0 : qb0;
    bf16x8 q1 = (0 <= pSw) ? qa1 : qb1;
#pragma unroll
    for (int kk = 0; kk < 64; kk += 32) {
      const int c8 = (kk >> 3) + lq;
      bf16x8 kf[4];
#pragma unroll
      for (int nj = 0; nj < 4; ++nj) kf[nj] = ldsfrag(sK[0], nj * 16 + lr, c8);
#pragma unroll
      for (int nj = 0; nj < 4; ++nj)
        sA_[nj] = __builtin_amdgcn_mfma_f32_16x16x32_bf16(kf[nj], kk ? q1 : q0, sA_[nj], 0, 0, 0);
    }
  }

  f32x4 o[4];  // O^T: o[nj][r] = O^T[dv = nj*16+lq*4+r][q = lr]
  float mL2 = -1e30f, lrp = 0.f;  // per-lane scalars (one q per lane)
#pragma unroll
  for (int j = 0; j < 4; ++j) o[j] = (f32x4){0.f, 0.f, 0.f, 0.f};

  const int b = bh >> 4, h = bh & 15;
  const int qloc = w * 16 + lr;  // in-tile q row of this lane

  // 8 full pairs (t=0..15 valid for both NT=16 and NT=17)
  for (int tb = 0; tb < 8; ++tb) {
    TRIP(tb * 2, sA_, sB_);
    TRIP(tb * 2 + 1, sB_, sA_);
  }
  if (NT == 17) TRIP(16, sA_, sB_);

  // partial write for q-tile b portion: side 0 = X prefix, side 1 = Y suffix
  {
    const int pi = bh * 16 + p;
    const int S = isX ? 0 : 1;
    float* poo = po + (size_t)(pi * 2 + S) * 4096;
    float* pmm = pml + (size_t)(pi * 2 + S) * 128;
    float ls = lrp;
    ls += __shfl_xor(ls, 16);
    ls += __shfl_xor(ls, 32);
    if (lq == 0) {
      float2 ml; ml.x = mL2; ml.y = ls;
      *(float2*)(pmm + qloc * 2) = ml;
    }
#pragma unroll
    for (int nj = 0; nj < 4; ++nj)
      *(f32x4*)(poo + qloc * 64 + nj * 16 + lq * 4) = o[nj];
  }
}

// ---------------- merge the two kv-partials of each split q-tile ----------------
__global__ __launch_bounds__(256) void k_merge(const float* __restrict__ po,
                                               const float* __restrict__ pml,
                                               u16* __restrict__ yb) {
  const int pi = blockIdx.x;  // bh*16 + p
  const int bh = pi >> 4, p = pi & 15;
  const int b = bh >> 4, h = bh & 15;
  const int q0 = (31 - p) << 6;
  const float* oX = po + (size_t)(pi * 2 + 0) * 4096;
  const float* oY = po + (size_t)(pi * 2 + 1) * 4096;
  const float* mlX = pml + (size_t)(pi * 2 + 0) * 128;
  const float* mlY = pml + (size_t)(pi * 2 + 1) * 128;
#pragma unroll
  for (int k = 0; k < 16; ++k) {
    int idx = k * 256 + threadIdx.x;
    int row = idx >> 6, col = idx & 63;
    float mX = mlX[row * 2], lX = mlX[row * 2 + 1];
    float mY = mlY[row * 2], lY = mlY[row * 2 + 1];
    float m = fmaxf(mX, mY);
    float aX = fexp2(mX - m), aY = fexp2(mY - m);
    float linv = 1.0f / (lX * aX + lY * aY);
    float y = (oX[idx] * aX + oY[idx] * aY) * linv;
    yb[((size_t)(b * 2048 + q0 + row)) * 1024 + h * 64 + col] = f2bf(y);
  }
}

// ---------------- GEMM2: R4 verbatim. out = y @ W_proj + b, 64x64 tiles,
// dim3(16,64) grid = 4/CU ----------------
__global__ __launch_bounds__(256) void k_gemm_proj(const u16* __restrict__ ybuf,
                                                   const u16* __restrict__ Wt,
                                                   const float* __restrict__ bias,
                                                   float* __restrict__ out) {
  __shared__ u16 sA[64 * 64], sB[64 * 64];  // 16KB
  f32x4 acc[2][2];
#pragma unroll
  for (int mi = 0; mi < 2; ++mi)
#pragma unroll
    for (int ni = 0; ni < 2; ++ni) acc[mi][ni] = (f32x4){0.f, 0.f, 0.f, 0.f};

  const int m0 = blockIdx.y * 64, n0 = blockIdx.x * 64;
  const int tid = threadIdx.x;
  const int lane = tid & 63, w = tid >> 6;
  const int wm = (w >> 1) << 5, wn = (w & 1) << 5;  // wave tile 32x32
  const int lr = lane & 15, lq = lane >> 4;
  const int srow = tid >> 3;
  const int gcol = ((tid & 7) ^ (srow & 7)) << 3;
  const u16* ag = ybuf + (size_t)(m0 + srow) * 1024 + gcol;
  const u16* bg = Wt + (size_t)(n0 + srow) * 1024 + gcol;
  u16* la = sA + w * 512;
  u16* lb = sB + w * 512;

  for (int k0 = 0; k0 < 1024; k0 += 64) {
    __syncthreads();
#pragma unroll
    for (int r = 0; r < 2; ++r) {
      gld_lds16(ag + (size_t)r * 32 * 1024 + k0, la + r * 2048);
      gld_lds16(bg + (size_t)r * 32 * 1024 + k0, lb + r * 2048);
    }
    __syncthreads();
#pragma unroll
    for (int kk = 0; kk < 64; kk += 32) {
      const int c8 = (kk >> 3) + lq;
      bf16x8 af[2], bfr[2];
#pragma unroll
      for (int i = 0; i < 2; ++i) {
        af[i] = ldsfrag(sA, wm + i * 16 + lr, c8);
        bfr[i] = ldsfrag(sB, wn + i * 16 + lr, c8);
      }
#pragma unroll
      for (int mi = 0; mi < 2; ++mi)
#pragma unroll
        for (int ni = 0; ni < 2; ++ni)
          acc[mi][ni] = __builtin_amdgcn_mfma_f32_16x16x32_bf16(af[mi], bfr[ni], acc[mi][ni], 0, 0, 0);
    }
  }

#pragma unroll
  for (int mi = 0; mi < 2; ++mi) {
    int gm = m0 + wm + mi * 16 + lq * 4;
#pragma unroll
    for (int ni = 0; ni < 2; ++ni) {
      int gn = n0 + wn + ni * 16 + lr;
      float bv = bias[gn];
#pragma unroll
      for (int r = 0; r < 4; ++r) out[(size_t)(gm + r) * 1024 + gn] = acc[mi][ni][r] + bv;
    }
  }
}

extern "C" void kernel_launch(void* const* d_in, const int* in_sizes, int n_in,
                              void* d_out, int out_size, void* d_ws, size_t ws_size,
                              hipStream_t stream) {
  const float* x = (const float*)d_in[0];       // [2,2048,1024]
  const float* W_attn = (const float*)d_in[1];  // [1024,3072]
  const float* b_attn = (const float*)d_in[2];  // [3072]
  const float* W_proj = (const float*)d_in[3];  // [1024,1024]
  const float* b_proj = (const float*)d_in[4];  // [1024]
  float* out = (float*)d_out;                   // [2,2048,1024] fp32

  u16* ws = (u16*)d_ws;
  u16* xb = ws;                   // 4096x1024 bf16          bytes [0, 8388608)
  u16* WaT = ws + 4194304;        // 3072x1024 (rows 2048.. used)  [8388608, 14680064)
  u16* qbuf = ws + 8388608;       // [32][2048][64]           [16777216, 25165824)
  u16* kbuf = ws + 12582912;      // [32][2048][64]           [25165824, 33554432)
  u16* vtb = ws + 16777216;       // [32][64][2048]           [33554432, 41943040)
  u16* ybuf = ws + 20971520;      // [4096][1024]             [41943040, 50331648)
  s8* xq = (s8*)ybuf;             // 4096x1024 i8 (aliases ybuf, dead until attn)
  s8* wq8 = (s8*)ybuf + 4194304;  // 2048x1024 i8
  float* po = (float*)ws;         // 512x2x4096 f32 partial O, aliases xb/WaT
                                  //   (dead after k_gemm_qkv): bytes [0, 16777216)
  float* pml = (float*)(ws + 25165824);  // 512x2x128 f32 (m,l) [50331648, 50855936)
  u16* WpT = ws + 25427968;       // 1024x1024 W_proj^T        [50855936, 52953088)

  k_prep<<<dim3(3072), dim3(256), 0, stream>>>(x, xb, xq, W_attn, WaT, wq8, W_proj, WpT);
  k_gemm_qkv<<<dim3(1536), dim3(256), 0, stream>>>(xb, xq, WaT, wq8, b_attn, qbuf, kbuf, vtb);
  k_attn<<<dim3(1024), dim3(256), 0, stream>>>(qbuf, kbuf, vtb, ybuf, po, pml);
  k_merge<<<dim3(512), dim3(256), 0, stream>>>(po, pml, ybuf);
  k_gemm_proj<<<dim3(16, 64), dim3(256), 0, stream>>>(ybuf, WpT, b_proj, out);
}

// Round 12
// 171.314 us; speedup vs baseline: 2.1012x; 1.0057x over previous
//
#include <hip/hip_runtime.h>

typedef unsigned short u16;
typedef unsigned char u8;
typedef signed char s8;
typedef unsigned int u32;
typedef short bf16x8 __attribute__((ext_vector_type(8)));
typedef float f32x4 __attribute__((ext_vector_type(4)));
typedef int i32x4 __attribute__((ext_vector_type(4)));

#define SXI 21.1666667f     /* 127/6.0  : x quant */
#define SWI 1058.3333f      /* 127/0.12 : W quant */
#define DEQ 4.4640015e-5f   /* (6.0*0.12)/(127*127) */

__device__ __forceinline__ u16 f2bf(float f) {
  union { float f; u32 u; } v; v.f = f;
  u32 r = v.u + 0x7fffu + ((v.u >> 16) & 1u);
  return (u16)(r >> 16);
}
__device__ __forceinline__ s8 q8(float v, float s) {
  float x = fminf(127.f, fmaxf(-127.f, v * s));
  return (s8)__float2int_rn(x);
}
__device__ __forceinline__ float fexp2(float x) {
#if __has_builtin(__builtin_amdgcn_exp2f)
  return __builtin_amdgcn_exp2f(x);
#else
  return exp2f(x);
#endif
}
__device__ __forceinline__ u32 cvtpk_bf16(float lo, float hi) {
  u32 r;
  asm("v_cvt_pk_bf16_f32 %0, %1, %2" : "=v"(r) : "v"(lo), "v"(hi));
  return r;
}

__device__ __forceinline__ void gld_lds16(const u16* g, u16* l) {
  __builtin_amdgcn_global_load_lds(
      (__attribute__((address_space(1))) u32*)(g),
      (__attribute__((address_space(3))) u32*)(l), 16, 0, 0);
}
__device__ __forceinline__ void gld_lds16b(const u8* g, u8* l) {
  __builtin_amdgcn_global_load_lds(
      (__attribute__((address_space(1))) u32*)(g),
      (__attribute__((address_space(3))) u32*)(l), 16, 0, 0);
}

// bf16 tiles: rows of 64 bf16 = 8 x 16B chunks, phys chunk = c ^ (row&7)
__device__ __forceinline__ bf16x8 ldsfrag(const u16* base, int row, int c8) {
  return *(const bf16x8*)(base + row * 64 + ((c8 ^ (row & 7)) << 3));
}
// i8 tiles: rows of 64 i8 = 4 x 16B chunks, phys chunk = c ^ swz4(row)
__device__ __forceinline__ int swz4(int r) { return (r & 3) ^ ((r >> 2) & 3); }

// ---------------- prep: x->bf16+i8, W_attn^T (qk i8, v bf16), W_proj^T ----------------
__global__ __launch_bounds__(256) void k_prep(const float* __restrict__ x, u16* __restrict__ xb,
                                              s8* __restrict__ xq,
                                              const float* __restrict__ Wa, u16* __restrict__ WaT,
                                              s8* __restrict__ wq8,
                                              const float* __restrict__ Wp, u16* __restrict__ WpT) {
  __shared__ float t[64][65];
  const int id = blockIdx.x;
  if (id < 2048) {
    int i = (id * 256 + threadIdx.x) * 8;
    const float4* p = (const float4*)(x + i);
    float4 a = p[0], b = p[1];
    uint4 o;
    o.x = (u32)f2bf(a.x) | ((u32)f2bf(a.y) << 16);
    o.y = (u32)f2bf(a.z) | ((u32)f2bf(a.w) << 16);
    o.z = (u32)f2bf(b.x) | ((u32)f2bf(b.y) << 16);
    o.w = (u32)f2bf(b.z) | ((u32)f2bf(b.w) << 16);
    *(uint4*)(xb + i) = o;
    u32 lo = (u32)(u8)q8(a.x, SXI) | ((u32)(u8)q8(a.y, SXI) << 8) |
             ((u32)(u8)q8(a.z, SXI) << 16) | ((u32)(u8)q8(a.w, SXI) << 24);
    u32 hi = (u32)(u8)q8(b.x, SXI) | ((u32)(u8)q8(b.y, SXI) << 8) |
             ((u32)(u8)q8(b.z, SXI) << 16) | ((u32)(u8)q8(b.w, SXI) << 24);
    uint2 oq; oq.x = lo; oq.y = hi;
    *(uint2*)(xq + i) = oq;
  } else if (id < 2816) {
    int q = id - 2048;
    int bx = q % 48, by = q / 48;
    int c0 = bx * 64, r0 = by * 64;
    int tx = threadIdx.x & 63, ty = threadIdx.x >> 6;
#pragma unroll
    for (int i = ty; i < 64; i += 4) t[i][tx] = Wa[(size_t)(r0 + i) * 3072 + c0 + tx];
    __syncthreads();
#pragma unroll
    for (int i = ty; i < 64; i += 4) {
      int row = c0 + i;
      if (row < 2048)
        wq8[(size_t)row * 1024 + r0 + tx] = q8(t[tx][i], SWI);
      else
        WaT[(size_t)row * 1024 + r0 + tx] = f2bf(t[tx][i]);
    }
  } else {
    int q = id - 2816;
    int bx = q & 15, by = q >> 4;
    int c0 = bx * 64, r0 = by * 64;
    int tx = threadIdx.x & 63, ty = threadIdx.x >> 6;
#pragma unroll
    for (int i = ty; i < 64; i += 4) t[i][tx] = Wp[(size_t)(r0 + i) * 1024 + c0 + tx];
    __syncthreads();
#pragma unroll
    for (int i = ty; i < 64; i += 4)
      WpT[(size_t)(c0 + i) * 1024 + r0 + tx] = f2bf(t[tx][i]);
  }
}

// ---------------- GEMM1 v15: i8 path gets counted-vmcnt dbuf (T3/T4 minimum):
// raw s_barrier + per-wave s_waitcnt vmcnt(3) — tile t+1's DMAs stay IN FLIGHT
// across the barrier (R5/R6 dbuf failed because __syncthreads drains vmcnt(0)).
// dbuf LDS = 24KB = v-path single-buffer -> 6 blocks/CU preserved.
// v-bf16 path: R4 verbatim (dbuf would need 48KB -> occupancy loss).
__global__ __launch_bounds__(256) void k_gemm_qkv(const u16* __restrict__ xb,
                                                  const s8* __restrict__ xq,
                                                  const u16* __restrict__ Wt,
                                                  const s8* __restrict__ wq8,
                                                  const float* __restrict__ bias,
                                                  u16* __restrict__ qb, u16* __restrict__ kb,
                                                  u16* __restrict__ vtb) {
  __shared__ __align__(16) u8 smem[24576];
  const int id = blockIdx.x;
  const int tid = threadIdx.x;
  const int lane = tid & 63, w = tid >> 6;
  const int lr = lane & 15, lq = lane >> 4;

  if (id < 1024) {
    // ---- int8 qk: 64x128 tile, counted-vmcnt dbuf. C[t][n], n in [0,2048) ----
    u8* la8 = smem;          // [2][64][64] i8, 8KB
    u8* lb8 = smem + 8192;   // [2][128][64] i8, 16KB
    const int wm = (w >> 1) << 5, wn = (w & 1) << 6;
    i32x4 acc[2][4];
#pragma unroll
    for (int mi = 0; mi < 2; ++mi)
#pragma unroll
      for (int ni = 0; ni < 4; ++ni) acc[mi][ni] = (i32x4){0, 0, 0, 0};
    const int m0 = (id >> 4) * 64, n0 = (id & 15) * 128;
    const int srow4 = tid >> 2;  // 0..63
    const int gcol4 = (((tid & 3) ^ swz4(srow4)) << 4);
    const u8* ag = (const u8*)xq + (size_t)(m0 + srow4) * 1024 + gcol4;
    const u8* bg = (const u8*)wq8 + (size_t)(n0 + srow4) * 1024 + gcol4;

    // stage tile kt (3 DMA instrs/wave) into buffer bi
#define STAGE_I8(kt, bi)                                                          \
    do {                                                                          \
      const int k0s = (kt) * 64;                                                  \
      gld_lds16b(ag + k0s, la8 + (bi) * 4096 + w * 1024);                         \
      _Pragma("unroll") for (int r = 0; r < 2; ++r)                               \
          gld_lds16b(bg + (size_t)r * 64 * 1024 + k0s,                            \
                     lb8 + (bi) * 8192 + r * 4096 + w * 1024);                    \
    } while (0)

    STAGE_I8(0, 0);
    STAGE_I8(1, 1);
    for (int t = 0; t < 16; ++t) {
      // own tile-t DMAs done (others' guaranteed by their waitcnt + barrier);
      // tile-(t+1)'s 3 DMAs remain in flight across the barrier.
      if (t < 15) asm volatile("s_waitcnt vmcnt(3)" ::: "memory");
      else        asm volatile("s_waitcnt vmcnt(0)" ::: "memory");
      __builtin_amdgcn_s_barrier();
      const u8* ca = la8 + (t & 1) * 4096;
      const u8* cb = lb8 + (t & 1) * 8192;
      i32x4 a[2], b[4];
#pragma unroll
      for (int mi = 0; mi < 2; ++mi) {
        int m = wm + mi * 16 + lr;
        a[mi] = *(const i32x4*)(ca + m * 64 + ((lq ^ swz4(m)) << 4));
      }
#pragma unroll
      for (int ni = 0; ni < 4; ++ni) {
        int n = wn + ni * 16 + lr;
        b[ni] = *(const i32x4*)(cb + n * 64 + ((lq ^ swz4(n)) << 4));
      }
#pragma unroll
      for (int mi = 0; mi < 2; ++mi)
#pragma unroll
        for (int ni = 0; ni < 4; ++ni)
          acc[mi][ni] = __builtin_amdgcn_mfma_i32_16x16x64_i8(a[mi], b[ni], acc[mi][ni], 0, 0, 0);
      if (t + 2 < 16) {
        __builtin_amdgcn_s_barrier();  // all waves done READING buf[t&1]
        STAGE_I8(t + 2, t & 1);
      }
    }
#undef STAGE_I8
#pragma unroll
    for (int mi = 0; mi < 2; ++mi) {
      int gm = m0 + wm + mi * 16 + lq * 4;
#pragma unroll
      for (int ni = 0; ni < 4; ++ni) {
        int gn = n0 + wn + ni * 16 + lr;
        float bv = bias[gn];
        int which = gn >> 10, head = (gn >> 6) & 15, hd = gn & 63;
#pragma unroll
        for (int r = 0; r < 4; ++r) {
          int row = gm + r;
          int b2 = row >> 11, tt = row & 2047;
          float v = (float)acc[mi][ni][r] * DEQ + bv;
          size_t bh = (size_t)(b2 * 16 + head);
          if (which == 0)
            qb[(bh * 2048 + tt) * 64 + hd] = f2bf(v * 0.18033688f);  // fold 1/sqrt(64)*log2(e)
          else
            kb[(bh * 2048 + tt) * 64 + hd] = f2bf(v);
        }
      }
    }
  } else {
    // ---- bf16 v^T: 64x128 tile (R4 verbatim). A = WaT rows 2048.., Bt = xb ----
    u16* sA = (u16*)smem;            // [64][64] u16, 8KB
    u16* sB = (u16*)(smem + 8192);   // [128][64] u16, 16KB
    const int wm = (w >> 1) << 5, wn = (w & 1) << 6;
    f32x4 acc[2][4];
#pragma unroll
    for (int mi = 0; mi < 2; ++mi)
#pragma unroll
      for (int ni = 0; ni < 4; ++ni) acc[mi][ni] = (f32x4){0.f, 0.f, 0.f, 0.f};
    const int t2 = id - 1024;
    const int m0 = (t2 >> 5) * 64, n0 = (t2 & 31) * 128;
    const int srow = tid >> 3;
    const int gcol = ((tid & 7) ^ (srow & 7)) << 3;
    const u16* ag = Wt + 2048 * 1024 + (size_t)(m0 + srow) * 1024 + gcol;
    const u16* bg = xb + (size_t)(n0 + srow) * 1024 + gcol;
    u16* la = sA + w * 512;
    u16* lb = sB + w * 512;

    for (int k0 = 0; k0 < 1024; k0 += 64) {
      __syncthreads();
#pragma unroll
      for (int r = 0; r < 2; ++r) gld_lds16(ag + (size_t)r * 32 * 1024 + k0, la + r * 2048);
#pragma unroll
      for (int r = 0; r < 4; ++r) gld_lds16(bg + (size_t)r * 32 * 1024 + k0, lb + r * 2048);
      __syncthreads();
#pragma unroll
      for (int kk = 0; kk < 64; kk += 32) {
        const int c8 = (kk >> 3) + lq;
        bf16x8 af[2], bfr[4];
#pragma unroll
        for (int i = 0; i < 2; ++i) af[i] = ldsfrag(sA, wm + i * 16 + lr, c8);
#pragma unroll
        for (int i = 0; i < 4; ++i) bfr[i] = ldsfrag(sB, wn + i * 16 + lr, c8);
#pragma unroll
        for (int mi = 0; mi < 2; ++mi)
#pragma unroll
          for (int ni = 0; ni < 4; ++ni)
            acc[mi][ni] = __builtin_amdgcn_mfma_f32_16x16x32_bf16(af[mi], bfr[ni], acc[mi][ni], 0, 0, 0);
      }
    }
#pragma unroll
    for (int mi = 0; mi < 2; ++mi) {
      int gm = m0 + wm + mi * 16 + lq * 4;  // dv base
      float4 bv = *(const float4*)(bias + 2048 + gm);
#pragma unroll
      for (int ni = 0; ni < 4; ++ni) {
        int gn = n0 + wn + ni * 16 + lr;  // t (coalesced)
        int b = gn >> 11, tt = gn & 2047;
#pragma unroll
        for (int r = 0; r < 4; ++r) {
          int dv = gm + r;
          float v = acc[mi][ni][r] + ((const float*)&bv)[r];
          vtb[((size_t)(b * 1024 + dv)) * 2048 + tt] = f2bf(v);
        }
      }
    }
  }
}

// ---------------- flash attention v12 (best measured, 41.7us): swapped QK^T,
// in-register P exchange, uniform-trip kv-split grid, setprio MFMA clusters,
// unroll-2 S/Sn ping-pong, tree-summed lrp.
#define TRIP(TT, SC, SN)                                                          \
  do {                                                                            \
    const int t = (TT);                                                           \
    __syncthreads();                                                              \
    if (t + 2 < NT) {                                                             \
      int j = t + 2;                                                              \
      int kv = isX ? ((j <= p) ? j : j - p - 1) : (kvY + j);                      \
      u16* lk = sK[t & 1] + w * 512;                                              \
      _Pragma("unroll") for (int r = 0; r < 2; ++r)                               \
          gld_lds16(kh + (size_t)(kv * 64 + r * 32 + srow) * 64 + gcol,           \
                    lk + r * 2048);                                               \
    }                                                                             \
    if (t + 1 < NT) {                                                             \
      int j = t + 1;                                                              \
      int kv = isX ? ((j <= p) ? j : j - p - 1) : (kvY + j);                      \
      u16* lv = sV[(t + 1) & 1] + w * 512;                                        \
      _Pragma("unroll") for (int r = 0; r < 2; ++r)                               \
          gld_lds16(vh + (size_t)(r * 32 + srow) * 2048 + kv * 64 + gcol,         \
                    lv + r * 2048);                                               \
    }                                                                             \
    if (t + 1 < NT) {                                                             \
      const u16* nK = sK[(t + 1) & 1];                                            \
      bf16x8 q0 = (t + 1 <= pSw) ? qa0 : qb0;                                     \
      bf16x8 q1 = (t + 1 <= pSw) ? qa1 : qb1;                                     \
      _Pragma("unroll") for (int nj = 0; nj < 4; ++nj) SN[nj] =                   \
          (f32x4){0.f, 0.f, 0.f, 0.f};                                            \
      __builtin_amdgcn_s_setprio(1);                                              \
      _Pragma("unroll") for (int kk = 0; kk < 64; kk += 32) {                     \
        const int c8 = (kk >> 3) + lq;                                            \
        bf16x8 kf[4];                                                             \
        _Pragma("unroll") for (int nj = 0; nj < 4; ++nj) kf[nj] =                 \
            ldsfrag(nK, nj * 16 + lr, c8);                                        \
        _Pragma("unroll") for (int nj = 0; nj < 4; ++nj) SN[nj] =                 \
            __builtin_amdgcn_mfma_f32_16x16x32_bf16(kf[nj], kk ? q1 : q0,         \
                                                    SN[nj], 0, 0, 0);             \
      }                                                                           \
      __builtin_amdgcn_s_setprio(0);                                              \
    }                                                                             \
    if (t == maskT) {                                                             \
      _Pragma("unroll") for (int nj = 0; nj < 4; ++nj)                            \
          _Pragma("unroll") for (int r = 0; r < 4; ++r) {                         \
        if (nj * 16 + lq * 4 + r > qloc) SC[nj][r] = -1e30f;                      \
      }                                                                           \
    }                                                                             \
    float mx = fmaxf(fmaxf(SC[0][0], SC[0][1]), fmaxf(SC[0][2], SC[0][3]));       \
    mx = fmaxf(mx, fmaxf(fmaxf(SC[1][0], SC[1][1]), fmaxf(SC[1][2], SC[1][3]))); \
    mx = fmaxf(mx, fmaxf(fmaxf(SC[2][0], SC[2][1]), fmaxf(SC[2][2], SC[2][3]))); \
    mx = fmaxf(mx, fmaxf(fmaxf(SC[3][0], SC[3][1]), fmaxf(SC[3][2], SC[3][3]))); \
    mx = fmaxf(mx, __shfl_xor(mx, 16));                                           \
    mx = fmaxf(mx, __shfl_xor(mx, 32));                                           \
    if (__any(mx > mL2 + 8.f)) {                                                  \
      float mn = fmaxf(mL2, mx);                                                  \
      float al = fexp2(mL2 - mn);                                                 \
      mL2 = mn;                                                                   \
      lrp *= al;                                                                  \
      _Pragma("unroll") for (int nj = 0; nj < 4; ++nj)                            \
          _Pragma("unroll") for (int r = 0; r < 4; ++r) o[nj][r] *= al;           \
    }                                                                             \
    {                                                                             \
      float rsA = 0.f, rsB = 0.f;                                                 \
      _Pragma("unroll") for (int nj = 0; nj < 4; ++nj) {                          \
        _Pragma("unroll") for (int r = 0; r < 4; ++r) SC[nj][r] =                 \
            fexp2(SC[nj][r] - mL2);                                               \
        float pa2 = (SC[nj][0] + SC[nj][1]) + (SC[nj][2] + SC[nj][3]);            \
        if (nj & 1) rsB += pa2; else rsA += pa2;                                  \
      }                                                                           \
      lrp += rsA + rsB;                                                           \
    }                                                                             \
    u32 pk0[4], pk1[4];                                                           \
    _Pragma("unroll") for (int nj = 0; nj < 4; ++nj) {                            \
      pk0[nj] = cvtpk_bf16(SC[nj][0], SC[nj][1]);                                 \
      pk1[nj] = cvtpk_bf16(SC[nj][2], SC[nj][3]);                                 \
    }                                                                             \
    u32 W000, W001, W010, W011, W100, W101, W110, W111;                           \
    {                                                                             \
      u32 v00 = bs0 ? pk0[1] : pk0[0];                                            \
      u32 v01 = bs0 ? pk1[1] : pk1[0];                                            \
      u32 v10 = bs0 ? pk0[0] : pk0[1];                                            \
      u32 v11 = bs0 ? pk1[0] : pk1[1];                                            \
      u32 r00 = (u32)__builtin_amdgcn_ds_bpermute(xadr0, (int)v00);               \
      u32 r01 = (u32)__builtin_amdgcn_ds_bpermute(xadr0, (int)v01);               \
      u32 r10 = (u32)__builtin_amdgcn_ds_bpermute(xadr1, (int)v10);               \
      u32 r11 = (u32)__builtin_amdgcn_ds_bpermute(xadr1, (int)v11);               \
      W000 = bd1 ? r10 : r00;                                                     \
      W001 = bd1 ? r11 : r01;                                                     \
      W010 = bd1 ? r00 : r10;                                                     \
      W011 = bd1 ? r01 : r11;                                                     \
      u32 u00 = bs0 ? pk0[3] : pk0[2];                                            \
      u32 u01 = bs0 ? pk1[3] : pk1[2];                                            \
      u32 u10 = bs0 ? pk0[2] : pk0[3];                                            \
      u32 u11 = bs0 ? pk1[2] : pk1[3];                                            \
      u32 t00 = (u32)__builtin_amdgcn_ds_bpermute(xadr0, (int)u00);               \
      u32 t01 = (u32)__builtin_amdgcn_ds_bpermute(xadr0, (int)u01);               \
      u32 t10 = (u32)__builtin_amdgcn_ds_bpermute(xadr1, (int)u10);               \
      u32 t11 = (u32)__builtin_amdgcn_ds_bpermute(xadr1, (int)u11);               \
      W100 = bd1 ? t10 : t00;                                                     \
      W101 = bd1 ? t11 : t01;                                                     \
      W110 = bd1 ? t00 : t10;                                                     \
      W111 = bd1 ? t01 : t11;                                                     \
    }                                                                             \
    union B8 { u32 u[4]; bf16x8 v; };                                             \
    B8 pb0u, pb1u;                                                                \
    pb0u.u[0] = W000; pb0u.u[1] = W001; pb0u.u[2] = W010; pb0u.u[3] = W011;       \
    pb1u.u[0] = W100; pb1u.u[1] = W101; pb1u.u[2] = W110; pb1u.u[3] = W111;       \
    {                                                                             \
      const u16* cV = sV[t & 1];                                                  \
      __builtin_amdgcn_s_setprio(1);                                              \
      _Pragma("unroll") for (int kkidx = 0; kkidx < 2; ++kkidx) {                 \
        const int c8 = kkidx * 4 + lq;                                            \
        bf16x8 pb = kkidx ? pb1u.v : pb0u.v;                                      \
        bf16x8 vf[4];                                                             \
        _Pragma("unroll") for (int nj = 0; nj < 4; ++nj) vf[nj] =                 \
            ldsfrag(cV, nj * 16 + lr, c8);                                        \
        _Pragma("unroll") for (int nj = 0; nj < 4; ++nj) o[nj] =                  \
            __builtin_amdgcn_mfma_f32_16x16x32_bf16(vf[nj], pb, o[nj], 0, 0, 0);  \
      }                                                                           \
      __builtin_amdgcn_s_setprio(0);                                              \
    }                                                                             \
    if (isX && t == p) {                                                          \
      float ls = lrp;                                                             \
      ls += __shfl_xor(ls, 16);                                                   \
      ls += __shfl_xor(ls, 32);                                                   \
      float inv = 1.0f / ls;                                                      \
      size_t base = ((size_t)(b * 2048 + (p << 6) + qloc)) * 1024 + h * 64;       \
      _Pragma("unroll") for (int nj = 0; nj < 4; ++nj) {                          \
        ushort4 sv;                                                               \
        sv.x = f2bf(o[nj][0] * inv);                                              \
        sv.y = f2bf(o[nj][1] * inv);                                              \
        sv.z = f2bf(o[nj][2] * inv);                                              \
        sv.w = f2bf(o[nj][3] * inv);                                              \
        *(ushort4*)(yb + base + nj * 16 + lq * 4) = sv;                           \
      }                                                                           \
      _Pragma("unroll") for (int j2 = 0; j2 < 4; ++j2) o[j2] =                    \
          (f32x4){0.f, 0.f, 0.f, 0.f};                                            \
      mL2 = -1e30f;                                                               \
      lrp = 0.f;                                                                  \
    }                                                                             \
  } while (0)

__global__ __launch_bounds__(256, 4) void k_attn(const u16* __restrict__ qbp,
                                                 const u16* __restrict__ kbp,
                                                 const u16* __restrict__ vtp,
                                                 u16* __restrict__ yb,
                                                 float* __restrict__ po,
                                                 float* __restrict__ pml) {
  __shared__ u16 sK[2][64 * 64];  // 16KB dbuf (stream pos i -> sK[i&1])
  __shared__ u16 sV[2][64 * 64];  // 16KB dbuf, [hd][kv]

  const int tid = threadIdx.x;
  const int lane = tid & 63, w = tid >> 6;
  const int lr = lane & 15, lq = lane >> 4;
  const int l = blockIdx.x;
  const int bh = l & 31;
  const int u = l >> 5;  // 0..31
  const bool isX = (u < 16);
  const int p = isX ? u : (u - 16);
  const int NT = isX ? 17 : 16;
  const int pSw = isX ? p : -1;    // stream pos <= pSw uses q-tile a
  const int maskT = isX ? p : 15;  // diagonal-mask trip
  const int kvY = 16 - p;          // Y: kv = kvY + t

  const u16* qh = qbp + (size_t)bh * (2048 * 64);
  const u16* kh = kbp + (size_t)bh * (2048 * 64);
  const u16* vh = vtp + (size_t)bh * (64 * 2048);

  // Q fragments (B-operand of swapped mfma; layout identical to A): lane q=lr
  bf16x8 qa0, qa1, qb0, qb1;
  {
    const u16* qpb = qh + (size_t)(((31 - p) << 6) + w * 16 + lr) * 64 + lq * 8;
    qb0 = *(const bf16x8*)(qpb);
    qb1 = *(const bf16x8*)(qpb + 32);
    if (isX) {
      const u16* qpa = qh + (size_t)((p << 6) + w * 16 + lr) * 64 + lq * 8;
      qa0 = *(const bf16x8*)(qpa);
      qa1 = *(const bf16x8*)(qpa + 32);
    } else {
      qa0 = qb0; qa1 = qb1;
    }
  }

  const int srow = tid >> 3;                       // 0..31
  const int gcol = ((tid & 7) ^ (srow & 7)) << 3;  // swizzled 16B chunk

  // bpermute addrs for the 4-lane (lq-group) exchange; partner has same lr
  const int xadr0 = 4 * (lr + 16 * (2 * (lq & 1) + (lq >> 1)));
  const int xadr1 = xadr0 ^ 64;
  const bool bs0 = (lq & 1) != 0;
  const bool bd1 = (lq >> 1) != 0;

  {  // prologue staging: K(stream0), K(stream1), V(stream0)
    const int kv0 = isX ? 0 : kvY;
    const int kv1 = isX ? ((1 <= p) ? 1 : 0) : (kvY + 1);
    u16* lk0 = sK[0] + w * 512;
    u16* lk1 = sK[1] + w * 512;
    u16* lv0 = sV[0] + w * 512;
#pragma unroll
    for (int r = 0; r < 2; ++r) {
      gld_lds16(kh + (size_t)(kv0 * 64 + r * 32 + srow) * 64 + gcol, lk0 + r * 2048);
      gld_lds16(vh + (size_t)(r * 32 + srow) * 2048 + kv0 * 64 + gcol, lv0 + r * 2048);
      gld_lds16(kh + (size_t)(kv1 * 64 + r * 32 + srow) * 64 + gcol, lk1 + r * 2048);
    }
  }
  __syncthreads();

  // S^T(stream 0) = K(0) Q^T : sA_[nj][r] = S^T[kv = nj*16+lq*4+r][q = lr]
  f32x4 sA_[4], sB_[4];
#pragma unroll
  for (int nj = 0; nj < 4; ++nj) sA_[nj] = (f32x4){0.f, 0.f, 0.f, 0.f};
  {
    bf16x8 q0 = (0 <= pSw) ? qa0 : qb0;
    bf16x8 q1 = (0 <= pSw) ? qa1 : qb1;
#pragma unroll
    for (int kk = 0; kk < 64; kk += 32) {
      const int c8 = (kk >> 3) + lq;
      bf16x8 kf[4];
#pragma unroll
      for (int nj = 0; nj < 4; ++nj) kf[nj] = ldsfrag(sK[0], nj * 16 + lr, c8);
#pragma unroll
      for (int nj = 0; nj < 4; ++nj)
        sA_[nj] = __builtin_amdgcn_mfma_f32_16x16x32_bf16(kf[nj], kk ? q1 : q0, sA_[nj], 0, 0, 0);
    }
  }

  f32x4 o[4];  // O^T: o[nj][r] = O^T[dv = nj*16+lq*4+r][q = lr]
  float mL2 = -1e30f, lrp = 0.f;  // per-lane scalars (one q per lane)
#pragma unroll
  for (int j = 0; j < 4; ++j) o[j] = (f32x4){0.f, 0.f, 0.f, 0.f};

  const int b = bh >> 4, h = bh & 15;
  const int qloc = w * 16 + lr;  // in-tile q row of this lane

  // 8 full pairs (t=0..15 valid for both NT=16 and NT=17)
  for (int tb = 0; tb < 8; ++tb) {
    TRIP(tb * 2, sA_, sB_);
    TRIP(tb * 2 + 1, sB_, sA_);
  }
  if (NT == 17) TRIP(16, sA_, sB_);

  // partial write for q-tile b portion: side 0 = X prefix, side 1 = Y suffix
  {
    const int pi = bh * 16 + p;
    const int S = isX ? 0 : 1;
    float* poo = po + (size_t)(pi * 2 + S) * 4096;
    float* pmm = pml + (size_t)(pi * 2 + S) * 128;
    float ls = lrp;
    ls += __shfl_xor(ls, 16);
    ls += __shfl_xor(ls, 32);
    if (lq == 0) {
      float2 ml; ml.x = mL2; ml.y = ls;
      *(float2*)(pmm + qloc * 2) = ml;
    }
#pragma unroll
    for (int nj = 0; nj < 4; ++nj)
      *(f32x4*)(poo + qloc * 64 + nj * 16 + lq * 4) = o[nj];
  }
}

// ---------------- merge the two kv-partials of each split q-tile ----------------
__global__ __launch_bounds__(256) void k_merge(const float* __restrict__ po,
                                               const float* __restrict__ pml,
                                               u16* __restrict__ yb) {
  const int pi = blockIdx.x;  // bh*16 + p
  const int bh = pi >> 4, p = pi & 15;
  const int b = bh >> 4, h = bh & 15;
  const int q0 = (31 - p) << 6;
  const float* oX = po + (size_t)(pi * 2 + 0) * 4096;
  const float* oY = po + (size_t)(pi * 2 + 1) * 4096;
  const float* mlX = pml + (size_t)(pi * 2 + 0) * 128;
  const float* mlY = pml + (size_t)(pi * 2 + 1) * 128;
#pragma unroll
  for (int k = 0; k < 16; ++k) {
    int idx = k * 256 + threadIdx.x;
    int row = idx >> 6, col = idx & 63;
    float mX = mlX[row * 2], lX = mlX[row * 2 + 1];
    float mY = mlY[row * 2], lY = mlY[row * 2 + 1];
    float m = fmaxf(mX, mY);
    float aX = fexp2(mX - m), aY = fexp2(mY - m);
    float linv = 1.0f / (lX * aX + lY * aY);
    float y = (oX[idx] * aX + oY[idx] * aY) * linv;
    yb[((size_t)(b * 2048 + q0 + row)) * 1024 + h * 64 + col] = f2bf(y);
  }
}

// ---------------- GEMM2 v15: 64x64 tiles, counted-vmcnt dbuf (32KB, 4/CU
// unchanged). Raw s_barrier + vmcnt(4): tile t+1's DMAs stay in flight.
__global__ __launch_bounds__(256) void k_gemm_proj(const u16* __restrict__ ybuf,
                                                   const u16* __restrict__ Wt,
                                                   const float* __restrict__ bias,
                                                   float* __restrict__ out) {
  __shared__ u16 sA[2][64 * 64], sB[2][64 * 64];  // 32KB dbuf
  f32x4 acc[2][2];
#pragma unroll
  for (int mi = 0; mi < 2; ++mi)
#pragma unroll
    for (int ni = 0; ni < 2; ++ni) acc[mi][ni] = (f32x4){0.f, 0.f, 0.f, 0.f};

  const int m0 = blockIdx.y * 64, n0 = blockIdx.x * 64;
  const int tid = threadIdx.x;
  const int lane = tid & 63, w = tid >> 6;
  const int wm = (w >> 1) << 5, wn = (w & 1) << 5;  // wave tile 32x32
  const int lr = lane & 15, lq = lane >> 4;
  const int srow = tid >> 3;
  const int gcol = ((tid & 7) ^ (srow & 7)) << 3;
  const u16* ag = ybuf + (size_t)(m0 + srow) * 1024 + gcol;
  const u16* bg = Wt + (size_t)(n0 + srow) * 1024 + gcol;

  // stage tile kt (4 DMA instrs/wave) into buffer bi
#define STAGE_P(kt, bi)                                                           \
  do {                                                                            \
    const int k0s = (kt) * 64;                                                    \
    _Pragma("unroll") for (int r = 0; r < 2; ++r) {                               \
      gld_lds16(ag + (size_t)r * 32 * 1024 + k0s, sA[bi] + w * 512 + r * 2048);   \
      gld_lds16(bg + (size_t)r * 32 * 1024 + k0s, sB[bi] + w * 512 + r * 2048);   \
    }                                                                             \
  } while (0)

  STAGE_P(0, 0);
  STAGE_P(1, 1);
  for (int t = 0; t < 16; ++t) {
    if (t < 15) asm volatile("s_waitcnt vmcnt(4)" ::: "memory");
    else        asm volatile("s_waitcnt vmcnt(0)" ::: "memory");
    __builtin_amdgcn_s_barrier();
    const u16* cA = sA[t & 1];
    const u16* cB = sB[t & 1];
#pragma unroll
    for (int kk = 0; kk < 64; kk += 32) {
      const int c8 = (kk >> 3) + lq;
      bf16x8 af[2], bfr[2];
#pragma unroll
      for (int i = 0; i < 2; ++i) {
        af[i] = ldsfrag(cA, wm + i * 16 + lr, c8);
        bfr[i] = ldsfrag(cB, wn + i * 16 + lr, c8);
      }
#pragma unroll
      for (int mi = 0; mi < 2; ++mi)
#pragma unroll
        for (int ni = 0; ni < 2; ++ni)
          acc[mi][ni] = __builtin_amdgcn_mfma_f32_16x16x32_bf16(af[mi], bfr[ni], acc[mi][ni], 0, 0, 0);
    }
    if (t + 2 < 16) {
      __builtin_amdgcn_s_barrier();  // all waves done reading buf[t&1]
      STAGE_P(t + 2, t & 1);
    }
  }
#undef STAGE_P

#pragma unroll
  for (int mi = 0; mi < 2; ++mi) {
    int gm = m0 + wm + mi * 16 + lq * 4;
#pragma unroll
    for (int ni = 0; ni < 2; ++ni) {
      int gn = n0 + wn + ni * 16 + lr;
      float bv = bias[gn];
#pragma unroll
      for (int r = 0; r < 4; ++r) out[(size_t)(gm + r) * 1024 + gn] = acc[mi][ni][r] + bv;
    }
  }
}

extern "C" void kernel_launch(void* const* d_in, const int* in_sizes, int n_in,
                              void* d_out, int out_size, void* d_ws, size_t ws_size,
                              hipStream_t stream) {
  const float* x = (const float*)d_in[0];       // [2,2048,1024]
  const float* W_attn = (const float*)d_in[1];  // [1024,3072]
  const float* b_attn = (const float*)d_in[2];  // [3072]
  const float* W_proj = (const float*)d_in[3];  // [1024,1024]
  const float* b_proj = (const float*)d_in[4];  // [1024]
  float* out = (float*)d_out;                   // [2,2048,1024] fp32

  u16* ws = (u16*)d_ws;
  u16* xb = ws;                   // 4096x1024 bf16          bytes [0, 8388608)
  u16* WaT = ws + 4194304;        // 3072x1024 (rows 2048.. used)  [8388608, 14680064)
  u16* qbuf = ws + 8388608;       // [32][2048][64]           [16777216, 25165824)
  u16* kbuf = ws + 12582912;      // [32][2048][64]           [25165824, 33554432)
  u16* vtb = ws + 16777216;       // [32][64][2048]           [33554432, 41943040)
  u16* ybuf = ws + 20971520;      // [4096][1024]             [41943040, 50331648)
  s8* xq = (s8*)ybuf;             // 4096x1024 i8 (aliases ybuf, dead until attn)
  s8* wq8 = (s8*)ybuf + 4194304;  // 2048x1024 i8
  float* po = (float*)ws;         // 512x2x4096 f32 partial O, aliases xb/WaT
                                  //   (dead after k_gemm_qkv): bytes [0, 16777216)
  float* pml = (float*)(ws + 25165824);  // 512x2x128 f32 (m,l) [50331648, 50855936)
  u16* WpT = ws + 25427968;       // 1024x1024 W_proj^T        [50855936, 52953088)

  k_prep<<<dim3(3072), dim3(256), 0, stream>>>(x, xb, xq, W_attn, WaT, wq8, W_proj, WpT);
  k_gemm_qkv<<<dim3(1536), dim3(256), 0, stream>>>(xb, xq, WaT, wq8, b_attn, qbuf, kbuf, vtb);
  k_attn<<<dim3(1024), dim3(256), 0, stream>>>(qbuf, kbuf, vtb, ybuf, po, pml);
  k_merge<<<dim3(512), dim3(256), 0, stream>>>(po, pml, ybuf);
  k_gemm_proj<<<dim3(16, 64), dim3(256), 0, stream>>>(ybuf, WpT, b_proj, out);
}

// Round 13
// 171.196 us; speedup vs baseline: 2.1027x; 1.0007x over previous
//
#include <hip/hip_runtime.h>

typedef unsigned short u16;
typedef unsigned char u8;
typedef signed char s8;
typedef unsigned int u32;
typedef short bf16x8 __attribute__((ext_vector_type(8)));
typedef float f32x4 __attribute__((ext_vector_type(4)));
typedef int i32x4 __attribute__((ext_vector_type(4)));

#define SXI 21.1666667f     /* 127/6.0  : x quant */
#define SWI 1058.3333f      /* 127/0.12 : W quant */
#define DEQ 4.4640015e-5f   /* (6.0*0.12)/(127*127) */

__device__ __forceinline__ u16 f2bf(float f) {
  union { float f; u32 u; } v; v.f = f;
  u32 r = v.u + 0x7fffu + ((v.u >> 16) & 1u);
  return (u16)(r >> 16);
}
__device__ __forceinline__ s8 q8(float v, float s) {
  float x = fminf(127.f, fmaxf(-127.f, v * s));
  return (s8)__float2int_rn(x);
}
__device__ __forceinline__ float fexp2(float x) {
#if __has_builtin(__builtin_amdgcn_exp2f)
  return __builtin_amdgcn_exp2f(x);
#else
  return exp2f(x);
#endif
}
__device__ __forceinline__ u32 cvtpk_bf16(float lo, float hi) {
  u32 r;
  asm("v_cvt_pk_bf16_f32 %0, %1, %2" : "=v"(r) : "v"(lo), "v"(hi));
  return r;
}

__device__ __forceinline__ void gld_lds16(const u16* g, u16* l) {
  __builtin_amdgcn_global_load_lds(
      (__attribute__((address_space(1))) u32*)(g),
      (__attribute__((address_space(3))) u32*)(l), 16, 0, 0);
}
__device__ __forceinline__ void gld_lds16b(const u8* g, u8* l) {
  __builtin_amdgcn_global_load_lds(
      (__attribute__((address_space(1))) u32*)(g),
      (__attribute__((address_space(3))) u32*)(l), 16, 0, 0);
}

// bf16 tiles: rows of 64 bf16 = 8 x 16B chunks, phys chunk = c ^ (row&7)
__device__ __forceinline__ bf16x8 ldsfrag(const u16* base, int row, int c8) {
  return *(const bf16x8*)(base + row * 64 + ((c8 ^ (row & 7)) << 3));
}
// i8 tiles: rows of 64 i8 = 4 x 16B chunks, phys chunk = c ^ swz4(row)
__device__ __forceinline__ int swz4(int r) { return (r & 3) ^ ((r >> 2) & 3); }

// ---------------- prep: x->bf16+i8, W_attn^T (qk i8, v bf16), W_proj^T ----------------
__global__ __launch_bounds__(256) void k_prep(const float* __restrict__ x, u16* __restrict__ xb,
                                              s8* __restrict__ xq,
                                              const float* __restrict__ Wa, u16* __restrict__ WaT,
                                              s8* __restrict__ wq8,
                                              const float* __restrict__ Wp, u16* __restrict__ WpT) {
  __shared__ float t[64][65];
  const int id = blockIdx.x;
  if (id < 2048) {
    int i = (id * 256 + threadIdx.x) * 8;
    const float4* p = (const float4*)(x + i);
    float4 a = p[0], b = p[1];
    uint4 o;
    o.x = (u32)f2bf(a.x) | ((u32)f2bf(a.y) << 16);
    o.y = (u32)f2bf(a.z) | ((u32)f2bf(a.w) << 16);
    o.z = (u32)f2bf(b.x) | ((u32)f2bf(b.y) << 16);
    o.w = (u32)f2bf(b.z) | ((u32)f2bf(b.w) << 16);
    *(uint4*)(xb + i) = o;
    u32 lo = (u32)(u8)q8(a.x, SXI) | ((u32)(u8)q8(a.y, SXI) << 8) |
             ((u32)(u8)q8(a.z, SXI) << 16) | ((u32)(u8)q8(a.w, SXI) << 24);
    u32 hi = (u32)(u8)q8(b.x, SXI) | ((u32)(u8)q8(b.y, SXI) << 8) |
             ((u32)(u8)q8(b.z, SXI) << 16) | ((u32)(u8)q8(b.w, SXI) << 24);
    uint2 oq; oq.x = lo; oq.y = hi;
    *(uint2*)(xq + i) = oq;
  } else if (id < 2816) {
    int q = id - 2048;
    int bx = q % 48, by = q / 48;
    int c0 = bx * 64, r0 = by * 64;
    int tx = threadIdx.x & 63, ty = threadIdx.x >> 6;
#pragma unroll
    for (int i = ty; i < 64; i += 4) t[i][tx] = Wa[(size_t)(r0 + i) * 3072 + c0 + tx];
    __syncthreads();
#pragma unroll
    for (int i = ty; i < 64; i += 4) {
      int row = c0 + i;
      if (row < 2048)
        wq8[(size_t)row * 1024 + r0 + tx] = q8(t[tx][i], SWI);
      else
        WaT[(size_t)row * 1024 + r0 + tx] = f2bf(t[tx][i]);
    }
  } else {
    int q = id - 2816;
    int bx = q & 15, by = q >> 4;
    int c0 = bx * 64, r0 = by * 64;
    int tx = threadIdx.x & 63, ty = threadIdx.x >> 6;
#pragma unroll
    for (int i = ty; i < 64; i += 4) t[i][tx] = Wp[(size_t)(r0 + i) * 1024 + c0 + tx];
    __syncthreads();
#pragma unroll
    for (int i = ty; i < 64; i += 4)
      WpT[(size_t)(c0 + i) * 1024 + r0 + tx] = f2bf(t[tx][i]);
  }
}

// ---------------- GEMM1 v16: fix heterogeneous tail. i8 path unchanged (R12
// counted-vmcnt dbuf, 1024 blocks). v-bf16 path retiled 64x128 -> 64x64 (1024
// blocks, clone of proven k_gemm_proj loop): grid 2048 at 6/CU resident gives
// 2 queued blocks/CU of BACKFILL — retiring short i8 blocks now backfill with
// v-blocks instead of idling their slot (same zero-backfill tail pathology
// measured in attn R2: occupancy 24.6%).
__global__ __launch_bounds__(256) void k_gemm_qkv(const u16* __restrict__ xb,
                                                  const s8* __restrict__ xq,
                                                  const u16* __restrict__ Wt,
                                                  const s8* __restrict__ wq8,
                                                  const float* __restrict__ bias,
                                                  u16* __restrict__ qb, u16* __restrict__ kb,
                                                  u16* __restrict__ vtb) {
  __shared__ __align__(16) u8 smem[24576];
  const int id = blockIdx.x;
  const int tid = threadIdx.x;
  const int lane = tid & 63, w = tid >> 6;
  const int lr = lane & 15, lq = lane >> 4;

  if (id < 1024) {
    // ---- int8 qk: 64x128 tile, counted-vmcnt dbuf. C[t][n], n in [0,2048) ----
    u8* la8 = smem;          // [2][64][64] i8, 8KB
    u8* lb8 = smem + 8192;   // [2][128][64] i8, 16KB
    const int wm = (w >> 1) << 5, wn = (w & 1) << 6;
    i32x4 acc[2][4];
#pragma unroll
    for (int mi = 0; mi < 2; ++mi)
#pragma unroll
      for (int ni = 0; ni < 4; ++ni) acc[mi][ni] = (i32x4){0, 0, 0, 0};
    const int m0 = (id >> 4) * 64, n0 = (id & 15) * 128;
    const int srow4 = tid >> 2;  // 0..63
    const int gcol4 = (((tid & 3) ^ swz4(srow4)) << 4);
    const u8* ag = (const u8*)xq + (size_t)(m0 + srow4) * 1024 + gcol4;
    const u8* bg = (const u8*)wq8 + (size_t)(n0 + srow4) * 1024 + gcol4;

#define STAGE_I8(kt, bi)                                                          \
    do {                                                                          \
      const int k0s = (kt) * 64;                                                  \
      gld_lds16b(ag + k0s, la8 + (bi) * 4096 + w * 1024);                         \
      _Pragma("unroll") for (int r = 0; r < 2; ++r)                               \
          gld_lds16b(bg + (size_t)r * 64 * 1024 + k0s,                            \
                     lb8 + (bi) * 8192 + r * 4096 + w * 1024);                    \
    } while (0)

    STAGE_I8(0, 0);
    STAGE_I8(1, 1);
    for (int t = 0; t < 16; ++t) {
      if (t < 15) asm volatile("s_waitcnt vmcnt(3)" ::: "memory");
      else        asm volatile("s_waitcnt vmcnt(0)" ::: "memory");
      __builtin_amdgcn_s_barrier();
      const u8* ca = la8 + (t & 1) * 4096;
      const u8* cb = lb8 + (t & 1) * 8192;
      i32x4 a[2], b[4];
#pragma unroll
      for (int mi = 0; mi < 2; ++mi) {
        int m = wm + mi * 16 + lr;
        a[mi] = *(const i32x4*)(ca + m * 64 + ((lq ^ swz4(m)) << 4));
      }
#pragma unroll
      for (int ni = 0; ni < 4; ++ni) {
        int n = wn + ni * 16 + lr;
        b[ni] = *(const i32x4*)(cb + n * 64 + ((lq ^ swz4(n)) << 4));
      }
#pragma unroll
      for (int mi = 0; mi < 2; ++mi)
#pragma unroll
        for (int ni = 0; ni < 4; ++ni)
          acc[mi][ni] = __builtin_amdgcn_mfma_i32_16x16x64_i8(a[mi], b[ni], acc[mi][ni], 0, 0, 0);
      if (t + 2 < 16) {
        __builtin_amdgcn_s_barrier();  // all waves done READING buf[t&1]
        STAGE_I8(t + 2, t & 1);
      }
    }
#undef STAGE_I8
#pragma unroll
    for (int mi = 0; mi < 2; ++mi) {
      int gm = m0 + wm + mi * 16 + lq * 4;
#pragma unroll
      for (int ni = 0; ni < 4; ++ni) {
        int gn = n0 + wn + ni * 16 + lr;
        float bv = bias[gn];
        int which = gn >> 10, head = (gn >> 6) & 15, hd = gn & 63;
#pragma unroll
        for (int r = 0; r < 4; ++r) {
          int row = gm + r;
          int b2 = row >> 11, tt = row & 2047;
          float v = (float)acc[mi][ni][r] * DEQ + bv;
          size_t bh = (size_t)(b2 * 16 + head);
          if (which == 0)
            qb[(bh * 2048 + tt) * 64 + hd] = f2bf(v * 0.18033688f);  // fold 1/sqrt(64)*log2(e)
          else
            kb[(bh * 2048 + tt) * 64 + hd] = f2bf(v);
        }
      }
    }
  } else {
    // ---- bf16 v^T: 64x64 tile (proj-loop clone). A = WaT rows 2048..
    // (M=1024=dv, 16 tiles), Bt = xb (N=4096=t, 64 tiles) -> 1024 blocks ----
    u16* sA = (u16*)smem;            // [64][64] u16, 8KB
    u16* sB = (u16*)(smem + 8192);   // [64][64] u16, 8KB
    const int wm = (w >> 1) << 5, wn = (w & 1) << 5;  // wave tile 32x32
    f32x4 acc[2][2];
#pragma unroll
    for (int mi = 0; mi < 2; ++mi)
#pragma unroll
      for (int ni = 0; ni < 2; ++ni) acc[mi][ni] = (f32x4){0.f, 0.f, 0.f, 0.f};
    const int t3 = id - 1024;
    const int m0 = (t3 >> 6) * 64, n0 = (t3 & 63) * 64;
    const int srow = tid >> 3;
    const int gcol = ((tid & 7) ^ (srow & 7)) << 3;
    const u16* ag = Wt + 2048 * 1024 + (size_t)(m0 + srow) * 1024 + gcol;
    const u16* bg = xb + (size_t)(n0 + srow) * 1024 + gcol;
    u16* la = sA + w * 512;
    u16* lb = sB + w * 512;

    for (int k0 = 0; k0 < 1024; k0 += 64) {
      __syncthreads();
#pragma unroll
      for (int r = 0; r < 2; ++r) {
        gld_lds16(ag + (size_t)r * 32 * 1024 + k0, la + r * 2048);
        gld_lds16(bg + (size_t)r * 32 * 1024 + k0, lb + r * 2048);
      }
      __syncthreads();
#pragma unroll
      for (int kk = 0; kk < 64; kk += 32) {
        const int c8 = (kk >> 3) + lq;
        bf16x8 af[2], bfr[2];
#pragma unroll
        for (int i = 0; i < 2; ++i) {
          af[i] = ldsfrag(sA, wm + i * 16 + lr, c8);
          bfr[i] = ldsfrag(sB, wn + i * 16 + lr, c8);
        }
#pragma unroll
        for (int mi = 0; mi < 2; ++mi)
#pragma unroll
          for (int ni = 0; ni < 2; ++ni)
            acc[mi][ni] = __builtin_amdgcn_mfma_f32_16x16x32_bf16(af[mi], bfr[ni], acc[mi][ni], 0, 0, 0);
      }
    }
#pragma unroll
    for (int mi = 0; mi < 2; ++mi) {
      int gm = m0 + wm + mi * 16 + lq * 4;  // dv base
      float4 bv = *(const float4*)(bias + 2048 + gm);
#pragma unroll
      for (int ni = 0; ni < 2; ++ni) {
        int gn = n0 + wn + ni * 16 + lr;  // t (coalesced)
        int b = gn >> 11, tt = gn & 2047;
#pragma unroll
        for (int r = 0; r < 4; ++r) {
          int dv = gm + r;
          float v = acc[mi][ni][r] + ((const float*)&bv)[r];
          vtb[((size_t)(b * 1024 + dv)) * 2048 + tt] = f2bf(v);
        }
      }
    }
  }
}

// ---------------- flash attention v12 (best measured, 41.7us): swapped QK^T,
// in-register P exchange, uniform-trip kv-split grid, setprio MFMA clusters,
// unroll-2 S/Sn ping-pong, tree-summed lrp.
#define TRIP(TT, SC, SN)                                                          \
  do {                                                                            \
    const int t = (TT);                                                           \
    __syncthreads();                                                              \
    if (t + 2 < NT) {                                                             \
      int j = t + 2;                                                              \
      int kv = isX ? ((j <= p) ? j : j - p - 1) : (kvY + j);                      \
      u16* lk = sK[t & 1] + w * 512;                                              \
      _Pragma("unroll") for (int r = 0; r < 2; ++r)                               \
          gld_lds16(kh + (size_t)(kv * 64 + r * 32 + srow) * 64 + gcol,           \
                    lk + r * 2048);                                               \
    }                                                                             \
    if (t + 1 < NT) {                                                             \
      int j = t + 1;                                                              \
      int kv = isX ? ((j <= p) ? j : j - p - 1) : (kvY + j);                      \
      u16* lv = sV[(t + 1) & 1] + w * 512;                                        \
      _Pragma("unroll") for (int r = 0; r < 2; ++r)                               \
          gld_lds16(vh + (size_t)(r * 32 + srow) * 2048 + kv * 64 + gcol,         \
                    lv + r * 2048);                                               \
    }                                                                             \
    if (t + 1 < NT) {                                                             \
      const u16* nK = sK[(t + 1) & 1];                                            \
      bf16x8 q0 = (t + 1 <= pSw) ? qa0 : qb0;                                     \
      bf16x8 q1 = (t + 1 <= pSw) ? qa1 : qb1;                                     \
      _Pragma("unroll") for (int nj = 0; nj < 4; ++nj) SN[nj] =                   \
          (f32x4){0.f, 0.f, 0.f, 0.f};                                            \
      __builtin_amdgcn_s_setprio(1);                                              \
      _Pragma("unroll") for (int kk = 0; kk < 64; kk += 32) {                     \
        const int c8 = (kk >> 3) + lq;                                            \
        bf16x8 kf[4];                                                             \
        _Pragma("unroll") for (int nj = 0; nj < 4; ++nj) kf[nj] =                 \
            ldsfrag(nK, nj * 16 + lr, c8);                                        \
        _Pragma("unroll") for (int nj = 0; nj < 4; ++nj) SN[nj] =                 \
            __builtin_amdgcn_mfma_f32_16x16x32_bf16(kf[nj], kk ? q1 : q0,         \
                                                    SN[nj], 0, 0, 0);             \
      }                                                                           \
      __builtin_amdgcn_s_setprio(0);                                              \
    }                                                                             \
    if (t == maskT) {                                                             \
      _Pragma("unroll") for (int nj = 0; nj < 4; ++nj)                            \
          _Pragma("unroll") for (int r = 0; r < 4; ++r) {                         \
        if (nj * 16 + lq * 4 + r > qloc) SC[nj][r] = -1e30f;                      \
      }                                                                           \
    }                                                                             \
    float mx = fmaxf(fmaxf(SC[0][0], SC[0][1]), fmaxf(SC[0][2], SC[0][3]));       \
    mx = fmaxf(mx, fmaxf(fmaxf(SC[1][0], SC[1][1]), fmaxf(SC[1][2], SC[1][3]))); \
    mx = fmaxf(mx, fmaxf(fmaxf(SC[2][0], SC[2][1]), fmaxf(SC[2][2], SC[2][3]))); \
    mx = fmaxf(mx, fmaxf(fmaxf(SC[3][0], SC[3][1]), fmaxf(SC[3][2], SC[3][3]))); \
    mx = fmaxf(mx, __shfl_xor(mx, 16));                                           \
    mx = fmaxf(mx, __shfl_xor(mx, 32));                                           \
    if (__any(mx > mL2 + 8.f)) {                                                  \
      float mn = fmaxf(mL2, mx);                                                  \
      float al = fexp2(mL2 - mn);                                                 \
      mL2 = mn;                                                                   \
      lrp *= al;                                                                  \
      _Pragma("unroll") for (int nj = 0; nj < 4; ++nj)                            \
          _Pragma("unroll") for (int r = 0; r < 4; ++r) o[nj][r] *= al;           \
    }                                                                             \
    {                                                                             \
      float rsA = 0.f, rsB = 0.f;                                                 \
      _Pragma("unroll") for (int nj = 0; nj < 4; ++nj) {                          \
        _Pragma("unroll") for (int r = 0; r < 4; ++r) SC[nj][r] =                 \
            fexp2(SC[nj][r] - mL2);                                               \
        float pa2 = (SC[nj][0] + SC[nj][1]) + (SC[nj][2] + SC[nj][3]);            \
        if (nj & 1) rsB += pa2; else rsA += pa2;                                  \
      }                                                                           \
      lrp += rsA + rsB;                                                           \
    }                                                                             \
    u32 pk0[4], pk1[4];                                                           \
    _Pragma("unroll") for (int nj = 0; nj < 4; ++nj) {                            \
      pk0[nj] = cvtpk_bf16(SC[nj][0], SC[nj][1]);                                 \
      pk1[nj] = cvtpk_bf16(SC[nj][2], SC[nj][3]);                                 \
    }                                                                             \
    u32 W000, W001, W010, W011, W100, W101, W110, W111;                           \
    {                                                                             \
      u32 v00 = bs0 ? pk0[1] : pk0[0];                                            \
      u32 v01 = bs0 ? pk1[1] : pk1[0];                                            \
      u32 v10 = bs0 ? pk0[0] : pk0[1];                                            \
      u32 v11 = bs0 ? pk1[0] : pk1[1];                                            \
      u32 r00 = (u32)__builtin_amdgcn_ds_bpermute(xadr0, (int)v00);               \
      u32 r01 = (u32)__builtin_amdgcn_ds_bpermute(xadr0, (int)v01);               \
      u32 r10 = (u32)__builtin_amdgcn_ds_bpermute(xadr1, (int)v10);               \
      u32 r11 = (u32)__builtin_amdgcn_ds_bpermute(xadr1, (int)v11);               \
      W000 = bd1 ? r10 : r00;                                                     \
      W001 = bd1 ? r11 : r01;                                                     \
      W010 = bd1 ? r00 : r10;                                                     \
      W011 = bd1 ? r01 : r11;                                                     \
      u32 u00 = bs0 ? pk0[3] : pk0[2];                                            \
      u32 u01 = bs0 ? pk1[3] : pk1[2];                                            \
      u32 u10 = bs0 ? pk0[2] : pk0[3];                                            \
      u32 u11 = bs0 ? pk1[2] : pk1[3];                                            \
      u32 t00 = (u32)__builtin_amdgcn_ds_bpermute(xadr0, (int)u00);               \
      u32 t01 = (u32)__builtin_amdgcn_ds_bpermute(xadr0, (int)u01);               \
      u32 t10 = (u32)__builtin_amdgcn_ds_bpermute(xadr1, (int)u10);               \
      u32 t11 = (u32)__builtin_amdgcn_ds_bpermute(xadr1, (int)u11);               \
      W100 = bd1 ? t10 : t00;                                                     \
      W101 = bd1 ? t11 : t01;                                                     \
      W110 = bd1 ? t00 : t10;                                                     \
      W111 = bd1 ? t01 : t11;                                                     \
    }                                                                             \
    union B8 { u32 u[4]; bf16x8 v; };                                             \
    B8 pb0u, pb1u;                                                                \
    pb0u.u[0] = W000; pb0u.u[1] = W001; pb0u.u[2] = W010; pb0u.u[3] = W011;       \
    pb1u.u[0] = W100; pb1u.u[1] = W101; pb1u.u[2] = W110; pb1u.u[3] = W111;       \
    {                                                                             \
      const u16* cV = sV[t & 1];                                                  \
      __builtin_amdgcn_s_setprio(1);                                              \
      _Pragma("unroll") for (int kkidx = 0; kkidx < 2; ++kkidx) {                 \
        const int c8 = kkidx * 4 + lq;                                            \
        bf16x8 pb = kkidx ? pb1u.v : pb0u.v;                                      \
        bf16x8 vf[4];                                                             \
        _Pragma("unroll") for (int nj = 0; nj < 4; ++nj) vf[nj] =                 \
            ldsfrag(cV, nj * 16 + lr, c8);                                        \
        _Pragma("unroll") for (int nj = 0; nj < 4; ++nj) o[nj] =                  \
            __builtin_amdgcn_mfma_f32_16x16x32_bf16(vf[nj], pb, o[nj], 0, 0, 0);  \
      }                                                                           \
      __builtin_amdgcn_s_setprio(0);                                              \
    }                                                                             \
    if (isX && t == p) {                                                          \
      float ls = lrp;                                                             \
      ls += __shfl_xor(ls, 16);                                                   \
      ls += __shfl_xor(ls, 32);                                                   \
      float inv = 1.0f / ls;                                                      \
      size_t base = ((size_t)(b * 2048 + (p << 6) + qloc)) * 1024 + h * 64;       \
      _Pragma("unroll") for (int nj = 0; nj < 4; ++nj) {                          \
        ushort4 sv;                                                               \
        sv.x = f2bf(o[nj][0] * inv);                                              \
        sv.y = f2bf(o[nj][1] * inv);                                              \
        sv.z = f2bf(o[nj][2] * inv);                                              \
        sv.w = f2bf(o[nj][3] * inv);                                              \
        *(ushort4*)(yb + base + nj * 16 + lq * 4) = sv;                           \
      }                                                                           \
      _Pragma("unroll") for (int j2 = 0; j2 < 4; ++j2) o[j2] =                    \
          (f32x4){0.f, 0.f, 0.f, 0.f};                                            \
      mL2 = -1e30f;                                                               \
      lrp = 0.f;                                                                  \
    }                                                                             \
  } while (0)

__global__ __launch_bounds__(256, 4) void k_attn(const u16* __restrict__ qbp,
                                                 const u16* __restrict__ kbp,
                                                 const u16* __restrict__ vtp,
                                                 u16* __restrict__ yb,
                                                 float* __restrict__ po,
                                                 float* __restrict__ pml) {
  __shared__ u16 sK[2][64 * 64];  // 16KB dbuf (stream pos i -> sK[i&1])
  __shared__ u16 sV[2][64 * 64];  // 16KB dbuf, [hd][kv]

  const int tid = threadIdx.x;
  const int lane = tid & 63, w = tid >> 6;
  const int lr = lane & 15, lq = lane >> 4;
  const int l = blockIdx.x;
  const int bh = l & 31;
  const int u = l >> 5;  // 0..31
  const bool isX = (u < 16);
  const int p = isX ? u : (u - 16);
  const int NT = isX ? 17 : 16;
  const int pSw = isX ? p : -1;    // stream pos <= pSw uses q-tile a
  const int maskT = isX ? p : 15;  // diagonal-mask trip
  const int kvY = 16 - p;          // Y: kv = kvY + t

  const u16* qh = qbp + (size_t)bh * (2048 * 64);
  const u16* kh = kbp + (size_t)bh * (2048 * 64);
  const u16* vh = vtp + (size_t)bh * (64 * 2048);

  // Q fragments (B-operand of swapped mfma; layout identical to A): lane q=lr
  bf16x8 qa0, qa1, qb0, qb1;
  {
    const u16* qpb = qh + (size_t)(((31 - p) << 6) + w * 16 + lr) * 64 + lq * 8;
    qb0 = *(const bf16x8*)(qpb);
    qb1 = *(const bf16x8*)(qpb + 32);
    if (isX) {
      const u16* qpa = qh + (size_t)((p << 6) + w * 16 + lr) * 64 + lq * 8;
      qa0 = *(const bf16x8*)(qpa);
      qa1 = *(const bf16x8*)(qpa + 32);
    } else {
      qa0 = qb0; qa1 = qb1;
    }
  }

  const int srow = tid >> 3;                       // 0..31
  const int gcol = ((tid & 7) ^ (srow & 7)) << 3;  // swizzled 16B chunk

  // bpermute addrs for the 4-lane (lq-group) exchange; partner has same lr
  const int xadr0 = 4 * (lr + 16 * (2 * (lq & 1) + (lq >> 1)));
  const int xadr1 = xadr0 ^ 64;
  const bool bs0 = (lq & 1) != 0;
  const bool bd1 = (lq >> 1) != 0;

  {  // prologue staging: K(stream0), K(stream1), V(stream0)
    const int kv0 = isX ? 0 : kvY;
    const int kv1 = isX ? ((1 <= p) ? 1 : 0) : (kvY + 1);
    u16* lk0 = sK[0] + w * 512;
    u16* lk1 = sK[1] + w * 512;
    u16* lv0 = sV[0] + w * 512;
#pragma unroll
    for (int r = 0; r < 2; ++r) {
      gld_lds16(kh + (size_t)(kv0 * 64 + r * 32 + srow) * 64 + gcol, lk0 + r * 2048);
      gld_lds16(vh + (size_t)(r * 32 + srow) * 2048 + kv0 * 64 + gcol, lv0 + r * 2048);
      gld_lds16(kh + (size_t)(kv1 * 64 + r * 32 + srow) * 64 + gcol, lk1 + r * 2048);
    }
  }
  __syncthreads();

  // S^T(stream 0) = K(0) Q^T : sA_[nj][r] = S^T[kv = nj*16+lq*4+r][q = lr]
  f32x4 sA_[4], sB_[4];
#pragma unroll
  for (int nj = 0; nj < 4; ++nj) sA_[nj] = (f32x4){0.f, 0.f, 0.f, 0.f};
  {
    bf16x8 q0 = (0 <= pSw) ? qa0 : qb0;
    bf16x8 q1 = (0 <= pSw) ? qa1 : qb1;
#pragma unroll
    for (int kk = 0; kk < 64; kk += 32) {
      const int c8 = (kk >> 3) + lq;
      bf16x8 kf[4];
#pragma unroll
      for (int nj = 0; nj < 4; ++nj) kf[nj] = ldsfrag(sK[0], nj * 16 + lr, c8);
#pragma unroll
      for (int nj = 0; nj < 4; ++nj)
        sA_[nj] = __builtin_amdgcn_mfma_f32_16x16x32_bf16(kf[nj], kk ? q1 : q0, sA_[nj], 0, 0, 0);
    }
  }

  f32x4 o[4];  // O^T: o[nj][r] = O^T[dv = nj*16+lq*4+r][q = lr]
  float mL2 = -1e30f, lrp = 0.f;  // per-lane scalars (one q per lane)
#pragma unroll
  for (int j = 0; j < 4; ++j) o[j] = (f32x4){0.f, 0.f, 0.f, 0.f};

  const int b = bh >> 4, h = bh & 15;
  const int qloc = w * 16 + lr;  // in-tile q row of this lane

  // 8 full pairs (t=0..15 valid for both NT=16 and NT=17)
  for (int tb = 0; tb < 8; ++tb) {
    TRIP(tb * 2, sA_, sB_);
    TRIP(tb * 2 + 1, sB_, sA_);
  }
  if (NT == 17) TRIP(16, sA_, sB_);

  // partial write for q-tile b portion: side 0 = X prefix, side 1 = Y suffix
  {
    const int pi = bh * 16 + p;
    const int S = isX ? 0 : 1;
    float* poo = po + (size_t)(pi * 2 + S) * 4096;
    float* pmm = pml + (size_t)(pi * 2 + S) * 128;
    float ls = lrp;
    ls += __shfl_xor(ls, 16);
    ls += __shfl_xor(ls, 32);
    if (lq == 0) {
      float2 ml; ml.x = mL2; ml.y = ls;
      *(float2*)(pmm + qloc * 2) = ml;
    }
#pragma unroll
    for (int nj = 0; nj < 4; ++nj)
      *(f32x4*)(poo + qloc * 64 + nj * 16 + lq * 4) = o[nj];
  }
}

// ---------------- merge the two kv-partials of each split q-tile ----------------
__global__ __launch_bounds__(256) void k_merge(const float* __restrict__ po,
                                               const float* __restrict__ pml,
                                               u16* __restrict__ yb) {
  const int pi = blockIdx.x;  // bh*16 + p
  const int bh = pi >> 4, p = pi & 15;
  const int b = bh >> 4, h = bh & 15;
  const int q0 = (31 - p) << 6;
  const float* oX = po + (size_t)(pi * 2 + 0) * 4096;
  const float* oY = po + (size_t)(pi * 2 + 1) * 4096;
  const float* mlX = pml + (size_t)(pi * 2 + 0) * 128;
  const float* mlY = pml + (size_t)(pi * 2 + 1) * 128;
#pragma unroll
  for (int k = 0; k < 16; ++k) {
    int idx = k * 256 + threadIdx.x;
    int row = idx >> 6, col = idx & 63;
    float mX = mlX[row * 2], lX = mlX[row * 2 + 1];
    float mY = mlY[row * 2], lY = mlY[row * 2 + 1];
    float m = fmaxf(mX, mY);
    float aX = fexp2(mX - m), aY = fexp2(mY - m);
    float linv = 1.0f / (lX * aX + lY * aY);
    float y = (oX[idx] * aX + oY[idx] * aY) * linv;
    yb[((size_t)(b * 2048 + q0 + row)) * 1024 + h * 64 + col] = f2bf(y);
  }
}

// ---------------- GEMM2 (R12): 64x64 tiles, counted-vmcnt dbuf (32KB, 4/CU).
__global__ __launch_bounds__(256) void k_gemm_proj(const u16* __restrict__ ybuf,
                                                   const u16* __restrict__ Wt,
                                                   const float* __restrict__ bias,
                                                   float* __restrict__ out) {
  __shared__ u16 sA[2][64 * 64], sB[2][64 * 64];  // 32KB dbuf
  f32x4 acc[2][2];
#pragma unroll
  for (int mi = 0; mi < 2; ++mi)
#pragma unroll
    for (int ni = 0; ni < 2; ++ni) acc[mi][ni] = (f32x4){0.f, 0.f, 0.f, 0.f};

  const int m0 = blockIdx.y * 64, n0 = blockIdx.x * 64;
  const int tid = threadIdx.x;
  const int lane = tid & 63, w = tid >> 6;
  const int wm = (w >> 1) << 5, wn = (w & 1) << 5;  // wave tile 32x32
  const int lr = lane & 15, lq = lane >> 4;
  const int srow = tid >> 3;
  const int gcol = ((tid & 7) ^ (srow & 7)) << 3;
  const u16* ag = ybuf + (size_t)(m0 + srow) * 1024 + gcol;
  const u16* bg = Wt + (size_t)(n0 + srow) * 1024 + gcol;

#define STAGE_P(kt, bi)                                                           \
  do {                                                                            \
    const int k0s = (kt) * 64;                                                    \
    _Pragma("unroll") for (int r = 0; r < 2; ++r) {                               \
      gld_lds16(ag + (size_t)r * 32 * 1024 + k0s, sA[bi] + w * 512 + r * 2048);   \
      gld_lds16(bg + (size_t)r * 32 * 1024 + k0s, sB[bi] + w * 512 + r * 2048);   \
    }                                                                             \
  } while (0)

  STAGE_P(0, 0);
  STAGE_P(1, 1);
  for (int t = 0; t < 16; ++t) {
    if (t < 15) asm volatile("s_waitcnt vmcnt(4)" ::: "memory");
    else        asm volatile("s_waitcnt vmcnt(0)" ::: "memory");
    __builtin_amdgcn_s_barrier();
    const u16* cA = sA[t & 1];
    const u16* cB = sB[t & 1];
#pragma unroll
    for (int kk = 0; kk < 64; kk += 32) {
      const int c8 = (kk >> 3) + lq;
      bf16x8 af[2], bfr[2];
#pragma unroll
      for (int i = 0; i < 2; ++i) {
        af[i] = ldsfrag(cA, wm + i * 16 + lr, c8);
        bfr[i] = ldsfrag(cB, wn + i * 16 + lr, c8);
      }
#pragma unroll
      for (int mi = 0; mi < 2; ++mi)
#pragma unroll
        for (int ni = 0; ni < 2; ++ni)
          acc[mi][ni] = __builtin_amdgcn_mfma_f32_16x16x32_bf16(af[mi], bfr[ni], acc[mi][ni], 0, 0, 0);
    }
    if (t + 2 < 16) {
      __builtin_amdgcn_s_barrier();  // all waves done reading buf[t&1]
      STAGE_P(t + 2, t & 1);
    }
  }
#undef STAGE_P

#pragma unroll
  for (int mi = 0; mi < 2; ++mi) {
    int gm = m0 + wm + mi * 16 + lq * 4;
#pragma unroll
    for (int ni = 0; ni < 2; ++ni) {
      int gn = n0 + wn + ni * 16 + lr;
      float bv = bias[gn];
#pragma unroll
      for (int r = 0; r < 4; ++r) out[(size_t)(gm + r) * 1024 + gn] = acc[mi][ni][r] + bv;
    }
  }
}

extern "C" void kernel_launch(void* const* d_in, const int* in_sizes, int n_in,
                              void* d_out, int out_size, void* d_ws, size_t ws_size,
                              hipStream_t stream) {
  const float* x = (const float*)d_in[0];       // [2,2048,1024]
  const float* W_attn = (const float*)d_in[1];  // [1024,3072]
  const float* b_attn = (const float*)d_in[2];  // [3072]
  const float* W_proj = (const float*)d_in[3];  // [1024,1024]
  const float* b_proj = (const float*)d_in[4];  // [1024]
  float* out = (float*)d_out;                   // [2,2048,1024] fp32

  u16* ws = (u16*)d_ws;
  u16* xb = ws;                   // 4096x1024 bf16          bytes [0, 8388608)
  u16* WaT = ws + 4194304;        // 3072x1024 (rows 2048.. used)  [8388608, 14680064)
  u16* qbuf = ws + 8388608;       // [32][2048][64]           [16777216, 25165824)
  u16* kbuf = ws + 12582912;      // [32][2048][64]           [25165824, 33554432)
  u16* vtb = ws + 16777216;       // [32][64][2048]           [33554432, 41943040)
  u16* ybuf = ws + 20971520;      // [4096][1024]             [41943040, 50331648)
  s8* xq = (s8*)ybuf;             // 4096x1024 i8 (aliases ybuf, dead until attn)
  s8* wq8 = (s8*)ybuf + 4194304;  // 2048x1024 i8
  float* po = (float*)ws;         // 512x2x4096 f32 partial O, aliases xb/WaT
                                  //   (dead after k_gemm_qkv): bytes [0, 16777216)
  float* pml = (float*)(ws + 25165824);  // 512x2x128 f32 (m,l) [50331648, 50855936)
  u16* WpT = ws + 25427968;       // 1024x1024 W_proj^T        [50855936, 52953088)

  k_prep<<<dim3(3072), dim3(256), 0, stream>>>(x, xb, xq, W_attn, WaT, wq8, W_proj, WpT);
  k_gemm_qkv<<<dim3(2048), dim3(256), 0, stream>>>(xb, xq, WaT, wq8, b_attn, qbuf, kbuf, vtb);
  k_attn<<<dim3(1024), dim3(256), 0, stream>>>(qbuf, kbuf, vtb, ybuf, po, pml);
  k_merge<<<dim3(512), dim3(256), 0, stream>>>(po, pml, ybuf);
  k_gemm_proj<<<dim3(16, 64), dim3(256), 0, stream>>>(ybuf, WpT, b_proj, out);
}